// Round 2
// baseline (269.952 us; speedup 1.0000x reference)
//
#include <hip/hip_runtime.h>
#include <cstdint>

// Problem constants (setup_inputs fixed: nx=2048, nz=256, B=512, S=10, k=25, T=30)
#define NX 2048
#define NZ 256
#define NB 512
#define NS 10
#define NK 25
#define NT 30
#define SBTOT (NS * NB)  // 5120

#define LOG2E 1.4426950408889634f
#define LN2 0.6931471805599453f

// d_out flat layout (all float32): q, samples_z, ps, xouts, loss
#define OFF_Q 0
#define OFF_SAMP (NB * NZ)
#define OFF_PS (OFF_SAMP + SBTOT * NZ)
#define OFF_XO (OFF_PS + SBTOT * NX)
#define OFF_LOSS (OFF_XO + SBTOT * NX)

typedef unsigned long long ull;
typedef __bf16 bf16x8 __attribute__((ext_vector_type(8)));
typedef float f32x4 __attribute__((ext_vector_type(4)));

// ---------------- JAX Threefry-2x32 (exact) ----------------
__host__ __device__ inline void tf2x32(uint32_t k0, uint32_t k1, uint32_t x0, uint32_t x1,
                                       uint32_t& o0, uint32_t& o1) {
  uint32_t k2 = k0 ^ k1 ^ 0x1BD11BDAu;
  x0 += k0; x1 += k1;
#define TF_R(r) { x0 += x1; x1 = (x1 << (r)) | (x1 >> (32 - (r))); x1 ^= x0; }
  TF_R(13) TF_R(15) TF_R(26) TF_R(6)
  x0 += k1; x1 += k2 + 1u;
  TF_R(17) TF_R(29) TF_R(16) TF_R(24)
  x0 += k2; x1 += k0 + 2u;
  TF_R(13) TF_R(15) TF_R(26) TF_R(6)
  x0 += k0; x1 += k1 + 3u;
  TF_R(17) TF_R(29) TF_R(16) TF_R(24)
  x0 += k1; x1 += k2 + 4u;
  TF_R(13) TF_R(15) TF_R(26) TF_R(6)
  x0 += k2; x1 += k0 + 5u;
#undef TF_R
  o0 = x0; o1 = x1;
}

// JAX threefry over iota(n): element i (h=n/2): i<h -> o0(i,i+h); else o1(i-h,i)
__device__ inline uint32_t tf_select(uint32_t k0, uint32_t k1, uint32_t i, uint32_t h) {
  bool lo = i < h;
  uint32_t x0 = lo ? i : i - h;
  uint32_t x1 = lo ? i + h : i;
  uint32_t o0, o1;
  tf2x32(k0, k1, x0, x1, o0, o1);
  return lo ? o0 : o1;
}

__device__ inline float tf_uniform(uint32_t k0, uint32_t k1, uint32_t i, uint32_t h) {
  uint32_t r = tf_select(k0, k1, i, h);
  return __uint_as_float(0x3f800000u | (r >> 9)) - 1.0f;  // [0,1), exactly JAX
}

__device__ inline float sigclip(float a) {
  float p = 1.0f / (1.0f + __expf(-a));
  return fminf(fmaxf(p, 1e-6f), 1.0f - 1e-6f);
}

__device__ inline ushort f2bf(float f) {  // RNE f32->bf16 (no NaN inputs here)
  uint32_t u = __float_as_uint(f);
  return (ushort)((u + 0x7FFFu + ((u >> 16) & 1u)) >> 16);
}

__device__ inline float blockReduceSum256(float v, volatile float* s4) {
#pragma unroll
  for (int o = 32; o > 0; o >>= 1) v += __shfl_down(v, o);
  __syncthreads();
  if ((threadIdx.x & 63) == 0) s4[threadIdx.x >> 6] = v;
  __syncthreads();
  return s4[0] + s4[1] + s4[2] + s4[3];
}

// ---------------- KP0: Vbf, Vkpad2, Uhi/Ulo split, xinbf, zero baseq, pz terms ----
__global__ __launch_bounds__(256) void kP0_prep(const float* __restrict__ V,
                                                const float* __restrict__ U,
                                                const float* __restrict__ xin,
                                                const float* __restrict__ z_bias,
                                                ushort* __restrict__ Vbf,
                                                ushort* __restrict__ Vkpad2,
                                                ushort* __restrict__ Uhi,
                                                ushort* __restrict__ Ulo,
                                                ushort* __restrict__ xinbf,
                                                float* __restrict__ baseq,
                                                float* __restrict__ d_lpz,
                                                float* __restrict__ basepz) {
  __shared__ float red[4];
  int e = blockIdx.x * 256 + threadIdx.x;  // < NX*NZ = 524288
  {  // V
    int x = e >> 8, k = e & 255;
    float v = V[e];
    Vbf[e] = f2bf(v);
    if (k < 32) Vkpad2[x * 32 + k] = (k < NK) ? f2bf(v * LOG2E) : (ushort)0;
  }
  {  // U split hi/lo (U is [NZ][NX], 524288 elements)
    float u = U[e];
    ushort hi = f2bf(u);
    Uhi[e] = hi;
    float hv = __uint_as_float((uint32_t)hi << 16);
    Ulo[e] = f2bf(u - hv);
  }
  {  // xin cast (1048576 elements, 2 per thread)
    xinbf[e] = (xin[e] > 0.5f) ? (ushort)0x3F80 : (ushort)0;
    int e2 = e + NX * NZ;
    xinbf[e2] = (xin[e2] > 0.5f) ? (ushort)0x3F80 : (ushort)0;
  }
  if (e < NB) baseq[e] = 0.0f;
  if (blockIdx.x == 0) {
    int z = threadIdx.x;
    float pz = sigclip(z_bias[z]);
    float lp = __logf(pz), l1 = __logf(1.0f - pz);
    d_lpz[z] = lp - l1;
    float s = blockReduceSum256(l1, red);
    if (z == 0) *basepz = s;
  }
}

// ---------------- KW: W[b][k] = sum_x (1-2*xin[b,x]) * bf16val(Vkpad2[x,k]) ----------
__global__ __launch_bounds__(256) void kW_signdot(const float* __restrict__ xin,
                                                  const ushort* __restrict__ Vkpad2,
                                                  float* __restrict__ W) {
  __shared__ float wred[4][NK];
  int b = blockIdx.x;
  int tid = threadIdx.x;
  float acc[NK];
#pragma unroll
  for (int j = 0; j < NK; ++j) acc[j] = 0.0f;
#pragma unroll
  for (int i = 0; i < 8; ++i) {
    int x = i * 256 + tid;
    float s = 1.0f - 2.0f * xin[(size_t)b * NX + x];
    const uint4* vp = (const uint4*)(Vkpad2 + (size_t)x * 32);
    uint4 q0 = vp[0], q1 = vp[1], q2 = vp[2], q3 = vp[3];
    uint32_t w[16] = {q0.x, q0.y, q0.z, q0.w, q1.x, q1.y, q1.z, q1.w,
                      q2.x, q2.y, q2.z, q2.w, q3.x, q3.y, q3.z, q3.w};
#pragma unroll
    for (int j = 0; j < NK; ++j) {
      uint32_t wd = w[j >> 1];
      float v = __uint_as_float((j & 1) ? (wd & 0xFFFF0000u) : (wd << 16));
      acc[j] = fmaf(s, v, acc[j]);
    }
  }
#pragma unroll
  for (int j = 0; j < NK; ++j) {
#pragma unroll
    for (int o = 1; o < 64; o <<= 1) acc[j] += __shfl_xor(acc[j], o);
  }
  if ((tid & 63) == 0) {
#pragma unroll
    for (int j = 0; j < NK; ++j) wred[tid >> 6][j] = acc[j];
  }
  __syncthreads();
  if (tid < NK) W[b * 32 + tid] = wred[0][tid] + wred[1][tid] + wred[2][tid] + wred[3][tid];
}

// ---------------- K1A: q-GEMM via MFMA hi/lo split-K (exact to ~fp32) ----------
__global__ __launch_bounds__(256) void k1a_mfma(const ushort* __restrict__ xinbf,
                                                const ushort* __restrict__ Uhi,
                                                const ushort* __restrict__ Ulo,
                                                const float* __restrict__ z_bias,
                                                float* __restrict__ outq,
                                                float* __restrict__ d_lq,
                                                float* __restrict__ baseq) {
  __shared__ float red[4][16][17];
  int tid = threadIdx.x;
  int wave = tid >> 6, lane = tid & 63, grp = lane >> 4, col = lane & 15;
  int b0 = (blockIdx.x >> 4) * 16;
  int z0 = (blockIdx.x & 15) * 16;
  f32x4 acc = {0.f, 0.f, 0.f, 0.f};
  const ushort* arow = xinbf + (size_t)(b0 + col) * NX + wave * 512 + grp * 8;
  const ushort* bhr = Uhi + (size_t)(z0 + col) * NX + wave * 512 + grp * 8;
  const ushort* blr = Ulo + (size_t)(z0 + col) * NX + wave * 512 + grp * 8;
#pragma unroll 4
  for (int s = 0; s < 16; ++s) {
    bf16x8 a = *(const bf16x8*)(arow + s * 32);
    bf16x8 bh = *(const bf16x8*)(bhr + s * 32);
    bf16x8 bl = *(const bf16x8*)(blr + s * 32);
    acc = __builtin_amdgcn_mfma_f32_16x16x32_bf16(a, bh, acc, 0, 0, 0);
    acc = __builtin_amdgcn_mfma_f32_16x16x32_bf16(a, bl, acc, 0, 0, 0);
  }
#pragma unroll
  for (int r = 0; r < 4; ++r) red[wave][grp * 4 + r][col] = acc[r];
  __syncthreads();
  int bi = tid >> 4, zi = tid & 15;
  float aa = red[0][bi][zi] + red[1][bi][zi] + red[2][bi][zi] + red[3][bi][zi] + z_bias[z0 + zi];
  int b = b0 + bi, z = z0 + zi;
  float q = sigclip(aa);
  outq[b * NZ + z] = q;
  float lq = __logf(q), l1 = __logf(1.0f - q);
  d_lq[b * NZ + z] = lq - l1;
  float s1 = l1;
#pragma unroll
  for (int o = 1; o < 16; o <<= 1) s1 += __shfl_xor(s1, o);
  if (zi == 0) atomicAdd(&baseq[b], s1);
}

// ---------------- K2: samples + packed bits + tails + FUSED proj/Syd (was K5) -----
__global__ __launch_bounds__(256) void k2_samples(const float* __restrict__ q,
                                                  const float* __restrict__ d_lq,
                                                  const float* __restrict__ d_lpz,
                                                  const ull* __restrict__ Ct,
                                                  const uint32_t* __restrict__ bpmask,
                                                  const float* __restrict__ W,
                                                  float* __restrict__ samp_out,
                                                  ushort* __restrict__ samp16,
                                                  ull* __restrict__ Spack,
                                                  float* __restrict__ qtail,
                                                  float* __restrict__ ptail,
                                                  uint32_t* __restrict__ projb,
                                                  float* __restrict__ Syd,
                                                  uint32_t kz0, uint32_t kz1) {
  __shared__ float red[4];
  __shared__ ull sp_sh[4];
  int sb = blockIdx.x;
  int z = threadIdx.x;
  int b = sb & (NB - 1);
  uint32_t i = (uint32_t)sb * NZ + z;
  const uint32_t h = (uint32_t)SBTOT * NZ / 2;
  float u = tf_uniform(kz0, kz1, i, h);
  float qv = q[b * NZ + z];
  int smp = (u < qv) ? 1 : 0;
  samp_out[i] = (float)smp;
  samp16[i] = smp ? (ushort)0x3F80 : (ushort)0;
  ull m = __ballot(smp);
  if ((z & 63) == 0) { Spack[sb * 4 + (z >> 6)] = m; sp_sh[z >> 6] = m; }
  float dq = (z >= NK && smp) ? d_lq[b * NZ + z] : 0.0f;
  float dp = (z >= NK && smp) ? d_lpz[z] : 0.0f;
  float sq = blockReduceSum256(dq, red);  // syncthreads inside publish sp_sh
  float sp = blockReduceSum256(dp, red);
  if (z == 0) { qtail[sb] = sq; ptail[sb] = sp; }
  // ---- fused k5: threads 0..31 compute projb/Syd for this sb ----
  if (z < 32) {
    int t = z;
    ull s0 = sp_sh[0], s1 = sp_sh[1], s2 = sp_sh[2], s3 = sp_sh[3];
    uint32_t s25 = (uint32_t)(s0 & 0x1FFFFFFull);
    const float* Wb = W + (size_t)b * 32;
    uint32_t out;
    float syd = 0.0f;
    if (t < NT) {
      uint32_t bp = bpmask[t];
      uint32_t pb = 0;
#pragma unroll
      for (int j = 0; j < NK; ++j) {
        const ull* C = Ct + (size_t)(t * NK + j) * 4;
        int par = __popcll(s0 & C[0]) + __popcll(s1 & C[1]) + __popcll(s2 & C[2]) + __popcll(s3 & C[3]);
        uint32_t bit = ((uint32_t)(par ^ (int)(bp >> j))) & 1u;
        pb |= bit << j;
        int d = (int)bit - (int)((s25 >> j) & 1u);
        syd = fmaf((float)d, Wb[j], syd);
      }
      out = pb;
    } else {
      out = s25;  // d = pb - s25 = 0
    }
    projb[sb * 32 + t] = out;
    Syd[sb * 32 + t] = syd;
  }
}

// ---------------- K3M: bf16 MFMA GEMM (operand-swapped): C[x][sb] = V·samp^T ------
// Block covers x-tile of 128 and PAIRED sb rows {sb0..sb0+31} u {sb0+2560..sb0+2591}
// (pair (sb, sb+SBTOT/2) shares one threefry-2x32 hash: o0/o1). Epilogue stages
// f32 logits through LDS so global stores are fully coalesced.
__global__ __launch_bounds__(256) void k3m_gemm(const ushort* __restrict__ samp16,
                                                const ushort* __restrict__ Vbf,
                                                const float* __restrict__ x_bias,
                                                ushort* __restrict__ base2,
                                                float* __restrict__ ps_out,
                                                float* __restrict__ xo_out,
                                                uint32_t kx0, uint32_t kx1) {
  // Aliased LDS: GEMM staging As(8KB)+Bs(4KB); epilogue 2 tiles [16][132] f32.
  __shared__ __align__(16) char smem[2 * 2112 * 4];  // 16896 B
  ushort* As = (ushort*)smem;          // V rows (x)     128*32 bf16
  ushort* Bs = (ushort*)(smem + 8192); // samp rows (sb)  64*32 bf16
  float* Tt = (float*)smem;            // epilogue tiles

  int tid = threadIdx.x;
  int wave = tid >> 6, lane = tid & 63, grp = lane >> 4, col = lane & 15;
  int x0 = blockIdx.x * 128;
  int sb0 = blockIdx.y * 32;  // first-half base; pair rows at sb0 + SBTOT/2
  f32x4 acc[2][4];
#pragma unroll
  for (int mi = 0; mi < 2; ++mi)
#pragma unroll
    for (int ni = 0; ni < 4; ++ni) acc[mi][ni] = (f32x4){0.f, 0.f, 0.f, 0.f};

  for (int k0 = 0; k0 < NZ; k0 += 32) {
    {
      int rowb = tid >> 2, kcb = (tid & 3) << 3;
      int sbrow = (rowb < 32) ? (sb0 + rowb) : (sb0 + 2528 + rowb);  // 2560+(rowb-32)
      *(uint4*)&Bs[rowb * 32 + kcb] = *(const uint4*)&samp16[(size_t)sbrow * NZ + k0 + kcb];
#pragma unroll
      for (int c = tid; c < 512; c += 256) {
        int rowa = c >> 2, kca = (c & 3) << 3;
        *(uint4*)&As[rowa * 32 + kca] = *(const uint4*)&Vbf[(size_t)(x0 + rowa) * NZ + k0 + kca];
      }
    }
    __syncthreads();
    bf16x8 af[2], bfv[4];
#pragma unroll
    for (int mi = 0; mi < 2; ++mi)
      af[mi] = *(const bf16x8*)&As[(wave * 32 + mi * 16 + col) * 32 + grp * 8];
#pragma unroll
    for (int ni = 0; ni < 4; ++ni)
      bfv[ni] = *(const bf16x8*)&Bs[(ni * 16 + col) * 32 + grp * 8];
#pragma unroll
    for (int mi = 0; mi < 2; ++mi)
#pragma unroll
      for (int ni = 0; ni < 4; ++ni)
        acc[mi][ni] = __builtin_amdgcn_mfma_f32_16x16x32_bf16(af[mi], bfv[ni], acc[mi][ni], 0, 0, 0);
    __syncthreads();
  }

  // ---- epilogue: LDS transpose for coalesced stores + paired threefry ----
  const uint32_t HH = (uint32_t)(SBTOT / 2) * (uint32_t)NX;  // 5242880
#pragma unroll
  for (int pi = 0; pi < 2; ++pi) {
    __syncthreads();  // previous reads of smem complete
#pragma unroll
    for (int mi = 0; mi < 2; ++mi) {
      int cbase = wave * 32 + mi * 16 + grp * 4;
      *(float4*)&Tt[col * 132 + cbase] = *(float4*)&acc[mi][pi];          // sb_a tile
      *(float4*)&Tt[2112 + col * 132 + cbase] = *(float4*)&acc[mi][pi + 2];  // sb_b tile
    }
    __syncthreads();
#pragma unroll
    for (int pass = 0; pass < 2; ++pass) {
      int r = pass * 8 + (tid >> 5);   // sb-local row 0..15
      int c = (tid & 31) * 4;          // x-local col, float4 granularity
      float4 t0 = *(float4*)&Tt[r * 132 + c];
      float4 t1 = *(float4*)&Tt[2112 + r * 132 + c];
      float4 xb4 = *(const float4*)(x_bias + x0 + c);
      int sb_a = sb0 + pi * 16 + r;                 // < SBTOT/2
      size_t off_a = (size_t)sb_a * NX + x0 + c;
      size_t off_b = off_a + (size_t)HH;
      float a0 = t0.x + xb4.x, a1 = t0.y + xb4.y, a2 = t0.z + xb4.z, a3 = t0.w + xb4.w;
      float b0 = t1.x + xb4.x, b1 = t1.y + xb4.y, b2 = t1.z + xb4.z, b3 = t1.w + xb4.w;
      uint2 bpa, bpb;
      bpa.x = (uint32_t)f2bf(a0 * LOG2E) | ((uint32_t)f2bf(a1 * LOG2E) << 16);
      bpa.y = (uint32_t)f2bf(a2 * LOG2E) | ((uint32_t)f2bf(a3 * LOG2E) << 16);
      bpb.x = (uint32_t)f2bf(b0 * LOG2E) | ((uint32_t)f2bf(b1 * LOG2E) << 16);
      bpb.y = (uint32_t)f2bf(b2 * LOG2E) | ((uint32_t)f2bf(b3 * LOG2E) << 16);
      *(uint2*)(base2 + off_a) = bpa;
      *(uint2*)(base2 + off_b) = bpb;
      float4 pva = make_float4(sigclip(a0), sigclip(a1), sigclip(a2), sigclip(a3));
      float4 pvb = make_float4(sigclip(b0), sigclip(b1), sigclip(b2), sigclip(b3));
      *(float4*)(ps_out + off_a) = pva;
      *(float4*)(ps_out + off_b) = pvb;
      // one threefry per paired element: x0=fi (first half), x1=fi+HH (second half)
      uint32_t fi = (uint32_t)off_a;
      uint32_t r0, r1;
      float4 xva, xvb;
      tf2x32(kx0, kx1, fi + 0u, fi + 0u + HH, r0, r1);
      xva.x = ((__uint_as_float(0x3f800000u | (r0 >> 9)) - 1.0f) < pva.x) ? 1.0f : 0.0f;
      xvb.x = ((__uint_as_float(0x3f800000u | (r1 >> 9)) - 1.0f) < pvb.x) ? 1.0f : 0.0f;
      tf2x32(kx0, kx1, fi + 1u, fi + 1u + HH, r0, r1);
      xva.y = ((__uint_as_float(0x3f800000u | (r0 >> 9)) - 1.0f) < pva.y) ? 1.0f : 0.0f;
      xvb.y = ((__uint_as_float(0x3f800000u | (r1 >> 9)) - 1.0f) < pvb.y) ? 1.0f : 0.0f;
      tf2x32(kx0, kx1, fi + 2u, fi + 2u + HH, r0, r1);
      xva.z = ((__uint_as_float(0x3f800000u | (r0 >> 9)) - 1.0f) < pva.z) ? 1.0f : 0.0f;
      xvb.z = ((__uint_as_float(0x3f800000u | (r1 >> 9)) - 1.0f) < pvb.z) ? 1.0f : 0.0f;
      tf2x32(kx0, kx1, fi + 3u, fi + 3u + HH, r0, r1);
      xva.w = ((__uint_as_float(0x3f800000u | (r0 >> 9)) - 1.0f) < pva.w) ? 1.0f : 0.0f;
      xvb.w = ((__uint_as_float(0x3f800000u | (r1 >> 9)) - 1.0f) < pvb.w) ? 1.0f : 0.0f;
      *(float4*)(xo_out + off_a) = xva;
      *(float4*)(xo_out + off_b) = xvb;
    }
  }
}

// ---------------- K4: GF(2) row reduce (parallel bit-gen + wave0 elimination) ----------------
__global__ __launch_bounds__(256) void k4_rowreduce(ull* __restrict__ Ct,
                                                    uint32_t* __restrict__ bpmask,
                                                    uint32_t kA0, uint32_t kA1,
                                                    uint32_t kb0, uint32_t kb1) {
  __shared__ uint32_t Aw[NK][8];
  __shared__ uint32_t bbsh[NK];
  int t = blockIdx.x;
  int tid = threadIdx.x;
  if (tid < NK * 8) {
    int r = tid >> 3, c = tid & 7;
    const uint32_t hA = (uint32_t)NT * NK * NZ / 2;
    uint32_t base_i = (uint32_t)(t * NK + r) * NZ + c * 32;
    uint32_t w = 0;
    for (int zz = 0; zz < 32; ++zz) {
      uint32_t rr = tf_select(kA0, kA1, base_i + zz, hA);
      w |= ((rr >> 31) ^ 1u) << zz;  // bit=1 iff u<0.5 (top bit 0)
    }
    Aw[r][c] = w;
  }
  if (tid < NK) {
    const uint32_t hb = (uint32_t)NT * NK / 2;
    uint32_t rb = tf_select(kb0, kb1, (uint32_t)(t * NK + tid), hb);
    bbsh[tid] = (rb >> 31) ^ 1u;
  }
  __syncthreads();
  if (tid >= 64) return;  // wave 0 does the elimination
  int lane = tid;
  ull w0 = 0, w1 = 0, w2 = 0, w3 = 0;
  uint32_t bbit = 0;
  if (lane < NK) {
    w0 = (ull)Aw[lane][0] | ((ull)Aw[lane][1] << 32);
    w1 = (ull)Aw[lane][2] | ((ull)Aw[lane][3] << 32);
    w2 = (ull)Aw[lane][4] | ((ull)Aw[lane][5] << 32);
    w3 = (ull)Aw[lane][6] | ((ull)Aw[lane][7] << 32);
    bbit = bbsh[lane];
  }
  for (int i = 0; i < NK; ++i) {
    int mybit = (int)((w0 >> i) & 1ull);
    ull mask = __ballot(lane < NK && mybit);
    ull cand = mask & (~0ull << i);
    int p = cand ? __builtin_ctzll(cand) : (NK - 1);
    int srcl = (lane == i) ? p : ((lane == p) ? i : lane);
    w0 = __shfl(w0, srcl); w1 = __shfl(w1, srcl); w2 = __shfl(w2, srcl); w3 = __shfl(w3, srcl);
    bbit = __shfl(bbit, srcl);
    ull p0 = __shfl(w0, i), p1 = __shfl(w1, i), p2 = __shfl(w2, i), p3 = __shfl(w3, i);
    uint32_t pvb = __shfl(bbit, i);
    int nb2 = (int)((w0 >> i) & 1ull);
    if (lane < NK && lane != i && nb2) {
      w0 ^= p0; w1 ^= p1; w2 ^= p2; w3 ^= p3; bbit ^= pvb;
    }
  }
  if (lane < NK) {
    w0 &= ~((1ull << NK) - 1ull);  // only columns z>=k feed proj
    ull* dstp = Ct + (size_t)(t * NK + lane) * 4;
    dstp[0] = w0; dstp[1] = w1; dstp[2] = w2; dstp[3] = w3;
  }
  ull bm = __ballot(lane < NK && bbit);
  if (lane == 0) bpmask[t] = (uint32_t)bm & 0x1FFFFFFu;
}

// ---------------- K6: logp_x via MFMA delta-GEMM + fused softplus (log2-space) ----------
__global__ __launch_bounds__(256) void k6_mfma(const ushort* __restrict__ base2,
                                               const ushort* __restrict__ Vkpad2,
                                               const float* __restrict__ xin,
                                               const uint32_t* __restrict__ projb,
                                               const ull* __restrict__ Spack,
                                               const float* __restrict__ Syd,
                                               float* __restrict__ logpx) {
  __shared__ float bvsm[NX];  // b2 per x — 8 KB
  __shared__ float lsum[4][32];
  __shared__ float red[4];
  int sb = blockIdx.x;
  int b = sb & (NB - 1);
  int tid = threadIdx.x;
  int wave = tid >> 6, lane = tid & 63;
  int grp = lane >> 4, col = lane & 15;
  // stage base2 row (bf16 -> f32) + analytic sum_x s*b2
  const uint4* b16p = (const uint4*)(base2 + (size_t)sb * NX);
  const float4* x4p = (const float4*)(xin + (size_t)b * NX);
  float sbacc = 0.0f;
  {
    uint4 bu = b16p[tid];
    float4 xv0 = x4p[tid * 2], xv1 = x4p[tid * 2 + 1];
    uint32_t wds[4] = {bu.x, bu.y, bu.z, bu.w};
    float bv[8];
#pragma unroll
    for (int j = 0; j < 8; ++j) {
      uint32_t wd = wds[j >> 1];
      bv[j] = __uint_as_float((j & 1) ? (wd & 0xFFFF0000u) : (wd << 16));
    }
    float sg[8] = {1.0f - 2.0f * xv0.x, 1.0f - 2.0f * xv0.y, 1.0f - 2.0f * xv0.z,
                   1.0f - 2.0f * xv0.w, 1.0f - 2.0f * xv1.x, 1.0f - 2.0f * xv1.y,
                   1.0f - 2.0f * xv1.z, 1.0f - 2.0f * xv1.w};
#pragma unroll
    for (int j = 0; j < 8; ++j) {
      bvsm[tid * 8 + j] = bv[j];
      sbacc = fmaf(sg[j], bv[j], sbacc);
    }
  }
  float Sb = blockReduceSum256(sbacc, red);  // includes syncthreads (guards bvsm)
  // A-frags: lane holds m=col (t within tile), k = grp*8+j
  uint32_t s25 = (uint32_t)(Spack[sb * 4] & 0x1FFFFFFull);
  uint32_t pb0 = projb[sb * 32 + col];
  uint32_t pb1 = projb[sb * 32 + 16 + col];
  bf16x8 a0, a1;
  union { ushort u; __bf16 hh; } cvt;
#pragma unroll
  for (int j = 0; j < 8; ++j) {
    int k = grp * 8 + j;
    int sbit = (int)((s25 >> k) & 1u);
    int d0 = (int)((pb0 >> k) & 1u) - sbit;
    int d1 = (int)((pb1 >> k) & 1u) - sbit;
    cvt.u = (ushort)(d0 == 0 ? 0 : (d0 > 0 ? 0x3F80 : 0xBF80)); a0[j] = cvt.hh;
    cvt.u = (ushort)(d1 == 0 ? 0 : (d1 > 0 ? 0x3F80 : 0xBF80)); a1[j] = cvt.hh;
  }
  float acca[8], pp[8];
#pragma unroll
  for (int r = 0; r < 8; ++r) { acca[r] = 0.0f; pp[r] = 1.0f; }
  const ushort* vkp = Vkpad2 + (size_t)(wave * 512 + col) * 32 + grp * 8;
  const float* bvp = bvsm + wave * 512 + col;
  bf16x8 bcur = *(const bf16x8*)(vkp);
#pragma unroll 8
  for (int i = 0; i < 32; ++i) {
    bf16x8 bnxt = bcur;
    if (i < 31) bnxt = *(const bf16x8*)(vkp + (size_t)(i + 1) * 512);
    f32x4 c0 = {0.f, 0.f, 0.f, 0.f}, c1 = {0.f, 0.f, 0.f, 0.f};
    c0 = __builtin_amdgcn_mfma_f32_16x16x32_bf16(a0, bcur, c0, 0, 0, 0);
    c1 = __builtin_amdgcn_mfma_f32_16x16x32_bf16(a1, bcur, c1, 0, 0, 0);
    float bs = bvp[i * 16];
#pragma unroll
    for (int r = 0; r < 4; ++r) {
      float y0 = bs + c0[r];
      acca[r] += fabsf(y0);
      pp[r] = fmaf(pp[r], __builtin_amdgcn_exp2f(-fabsf(y0)), pp[r]);
      float y1 = bs + c1[r];
      acca[4 + r] += fabsf(y1);
      pp[4 + r] = fmaf(pp[4 + r], __builtin_amdgcn_exp2f(-fabsf(y1)), pp[4 + r]);
    }
    bcur = bnxt;
  }
#pragma unroll
  for (int r = 0; r < 8; ++r) {
    float m = 0.5f * acca[r] + __log2f(pp[r]);
#pragma unroll
    for (int off = 1; off < 16; off <<= 1) m += __shfl_xor(m, off);
    if (col == 0) {
      int t = (r < 4) ? (grp * 4 + r) : (16 + grp * 4 + (r - 4));
      lsum[wave][t] = m;
    }
  }
  __syncthreads();
  if (tid < NT) {
    float tot = lsum[0][tid] + lsum[1][tid] + lsum[2][tid] + lsum[3][tid];
    tot += 0.5f * (Sb + Syd[sb * 32 + tid]);
    logpx[(size_t)tid * SBTOT + sb] = -LN2 * tot;
  }
}

// ---------------- K7: per-t weighted reduction, split over 8 b-chunks ----------------
__global__ __launch_bounds__(64) void k7_reduce(const float* __restrict__ logpx,
                                                const uint32_t* __restrict__ projb,
                                                const float* __restrict__ qtail,
                                                const float* __restrict__ ptail,
                                                const float* __restrict__ baseq,
                                                const float* __restrict__ d_lq,
                                                const float* __restrict__ d_lpz,
                                                const float* __restrict__ basepz,
                                                double* __restrict__ pelbo_part) {
  int t = blockIdx.x;
  int chunk = blockIdx.y;
  int lane = threadIdx.x;
  int b = chunk * 64 + lane;
  float dlq[NK];
#pragma unroll
  for (int j = 0; j < NK; ++j) dlq[j] = d_lq[b * NZ + j];
  float bq = baseq[b];
  float bpz = *basepz;
  float lq[NS], lp[NS];
#pragma unroll
  for (int s = 0; s < NS; ++s) {
    int sb = s * NB + b;
    uint32_t m = projb[sb * 32 + t];
    float sq = 0.0f, spv = 0.0f;
#pragma unroll
    for (int j = 0; j < NK; ++j) {
      float on = (float)((m >> j) & 1u);
      sq += on * dlq[j];
      spv += on * d_lpz[j];
    }
    lq[s] = bq + qtail[sb] + sq;
    lp[s] = logpx[t * SBTOT + sb] + bpz + ptail[sb] + spv;
  }
  float mx = lq[0];
#pragma unroll
  for (int s = 1; s < NS; ++s) mx = fmaxf(mx, lq[s]);
  float den = 0.0f, num = 0.0f;
#pragma unroll
  for (int s = 0; s < NS; ++s) {
    float w = __expf(lq[s] - mx);
    den += w;
    num += w * (lq[s] - lp[s]);
  }
  double v = (double)(num / den);
#pragma unroll
  for (int o = 32; o > 0; o >>= 1) v += __shfl_down(v, o);
  if (lane == 0) pelbo_part[t * 8 + chunk] = v;
}

// ---------------- K8: final loss (sum 8 parts per t, mean over t) ----------------
__global__ __launch_bounds__(64) void k8_loss(const double* __restrict__ pelbo_part,
                                              float* __restrict__ out_loss) {
  int t = threadIdx.x;
  double v = 0.0;
  if (t < NT) {
#pragma unroll
    for (int c = 0; c < 8; ++c) v += pelbo_part[t * 8 + c];
  }
#pragma unroll
  for (int o = 32; o > 0; o >>= 1) v += __shfl_down(v, o);
  if (t == 0) *out_loss = (float)(v / (double)NT);
}

extern "C" void kernel_launch(void* const* d_in, const int* in_sizes, int n_in,
                              void* d_out, int out_size, void* d_ws, size_t ws_size,
                              hipStream_t stream) {
  const float* xin = (const float*)d_in[0];
  const float* U = (const float*)d_in[1];
  const float* V = (const float*)d_in[2];
  const float* x_bias = (const float*)d_in[3];
  const float* z_bias = (const float*)d_in[4];
  float* out = (float*)d_out;

  char* p = (char*)d_ws;
  ushort* base2 = (ushort*)p;             p += (size_t)SBTOT * NX * 2;
  float* d_lq = (float*)p;                p += (size_t)NB * NZ * 4;
  float* baseq = (float*)p;               p += (size_t)NB * 4;
  float* d_lpz = (float*)p;               p += (size_t)NZ * 4;
  float* basepz = (float*)p;              p += 16;
  ull* Spack = (ull*)p;                   p += (size_t)SBTOT * 4 * 8;
  float* qtail = (float*)p;               p += (size_t)SBTOT * 4;
  float* ptail = (float*)p;               p += (size_t)SBTOT * 4;
  ull* Ct = (ull*)p;                      p += (size_t)NT * NK * 4 * 8;
  uint32_t* bpm = (uint32_t*)p;           p += 128;
  uint32_t* projb = (uint32_t*)p;         p += (size_t)SBTOT * 32 * 4;
  float* Syd = (float*)p;                 p += (size_t)SBTOT * 32 * 4;
  float* logpx = (float*)p;               p += (size_t)NT * SBTOT * 4;
  double* pelbo = (double*)p;             p += (size_t)NT * 8 * 8;
  ushort* Vkpad2 = (ushort*)p;            p += (size_t)NX * 32 * 2;
  ushort* Vbf = (ushort*)p;               p += (size_t)NX * NZ * 2;
  ushort* samp16 = (ushort*)p;            p += (size_t)SBTOT * NZ * 2;
  float* W = (float*)p;                   p += (size_t)NB * 32 * 4;
  ushort* Uhi = (ushort*)p;               p += (size_t)NZ * NX * 2;
  ushort* Ulo = (ushort*)p;               p += (size_t)NZ * NX * 2;
  ushort* xinbf = (ushort*)p;             p += (size_t)NB * NX * 2;
  (void)ws_size; (void)in_sizes; (void)n_in; (void)out_size;

  // JAX: key(42) -> split 4 -> kz,kx,kA,kb
  uint32_t o0[4], o1[4];
  for (int j = 0; j < 4; ++j) tf2x32(0u, 42u, (uint32_t)j, (uint32_t)(4 + j), o0[j], o1[j]);
  uint32_t kz0 = o0[0], kz1 = o0[1];
  uint32_t kx0 = o0[2], kx1 = o0[3];
  uint32_t kA0 = o1[0], kA1 = o1[1];
  uint32_t kb0 = o1[2], kb1 = o1[3];

  kP0_prep<<<NX * NZ / 256, 256, 0, stream>>>(V, U, xin, z_bias, Vbf, Vkpad2,
                                              Uhi, Ulo, xinbf, baseq, d_lpz, basepz);
  k4_rowreduce<<<NT, 256, 0, stream>>>(Ct, bpm, kA0, kA1, kb0, kb1);
  k1a_mfma<<<512, 256, 0, stream>>>(xinbf, Uhi, Ulo, z_bias, out + OFF_Q, d_lq, baseq);
  kW_signdot<<<NB, 256, 0, stream>>>(xin, Vkpad2, W);
  k2_samples<<<SBTOT, 256, 0, stream>>>(out + OFF_Q, d_lq, d_lpz, Ct, bpm, W,
                                        out + OFF_SAMP, samp16, Spack, qtail, ptail,
                                        projb, Syd, kz0, kz1);
  dim3 g3(NX / 128, SBTOT / 64);
  k3m_gemm<<<g3, 256, 0, stream>>>(samp16, Vbf, x_bias, base2,
                                   out + OFF_PS, out + OFF_XO, kx0, kx1);
  k6_mfma<<<SBTOT, 256, 0, stream>>>(base2, Vkpad2, xin, projb, Spack, Syd, logpx);
  dim3 g7(NT, 8);
  k7_reduce<<<g7, 64, 0, stream>>>(logpx, projb, qtail, ptail, baseq, d_lq,
                                   d_lpz, basepz, pelbo);
  k8_loss<<<1, 64, 0, stream>>>(pelbo, out + OFF_LOSS);
}

// Round 4
// 258.085 us; speedup vs baseline: 1.0460x; 1.0460x over previous
//
#include <hip/hip_runtime.h>
#include <cstdint>

// Problem constants (setup_inputs fixed: nx=2048, nz=256, B=512, S=10, k=25, T=30)
#define NX 2048
#define NZ 256
#define NB 512
#define NS 10
#define NK 25
#define NT 30
#define SBTOT (NS * NB)  // 5120

#define LOG2E 1.4426950408889634f
#define LN2 0.6931471805599453f

// d_out flat layout (all float32): q, samples_z, ps, xouts, loss
#define OFF_Q 0
#define OFF_SAMP (NB * NZ)
#define OFF_PS (OFF_SAMP + SBTOT * NZ)
#define OFF_XO (OFF_PS + SBTOT * NX)
#define OFF_LOSS (OFF_XO + SBTOT * NX)

typedef unsigned long long ull;
typedef __bf16 bf16x8 __attribute__((ext_vector_type(8)));
typedef float f32x4 __attribute__((ext_vector_type(4)));

// ---------------- JAX Threefry-2x32 (exact) ----------------
__host__ __device__ inline void tf2x32(uint32_t k0, uint32_t k1, uint32_t x0, uint32_t x1,
                                       uint32_t& o0, uint32_t& o1) {
  uint32_t k2 = k0 ^ k1 ^ 0x1BD11BDAu;
  x0 += k0; x1 += k1;
#define TF_R(r) { x0 += x1; x1 = (x1 << (r)) | (x1 >> (32 - (r))); x1 ^= x0; }
  TF_R(13) TF_R(15) TF_R(26) TF_R(6)
  x0 += k1; x1 += k2 + 1u;
  TF_R(17) TF_R(29) TF_R(16) TF_R(24)
  x0 += k2; x1 += k0 + 2u;
  TF_R(13) TF_R(15) TF_R(26) TF_R(6)
  x0 += k0; x1 += k1 + 3u;
  TF_R(17) TF_R(29) TF_R(16) TF_R(24)
  x0 += k1; x1 += k2 + 4u;
  TF_R(13) TF_R(15) TF_R(26) TF_R(6)
  x0 += k2; x1 += k0 + 5u;
#undef TF_R
  o0 = x0; o1 = x1;
}

// JAX threefry over iota(n): element i (h=n/2): i<h -> o0(i,i+h); else o1(i-h,i)
__device__ inline uint32_t tf_select(uint32_t k0, uint32_t k1, uint32_t i, uint32_t h) {
  bool lo = i < h;
  uint32_t x0 = lo ? i : i - h;
  uint32_t x1 = lo ? i + h : i;
  uint32_t o0, o1;
  tf2x32(k0, k1, x0, x1, o0, o1);
  return lo ? o0 : o1;
}

__device__ inline float tf_uniform(uint32_t k0, uint32_t k1, uint32_t i, uint32_t h) {
  uint32_t r = tf_select(k0, k1, i, h);
  return __uint_as_float(0x3f800000u | (r >> 9)) - 1.0f;  // [0,1), exactly JAX
}

__device__ inline float sigclip(float a) {
  float p = 1.0f / (1.0f + __expf(-a));
  return fminf(fmaxf(p, 1e-6f), 1.0f - 1e-6f);
}

__device__ inline ushort f2bf(float f) {  // RNE f32->bf16 (no NaN inputs here)
  uint32_t u = __float_as_uint(f);
  return (ushort)((u + 0x7FFFu + ((u >> 16) & 1u)) >> 16);
}

__device__ inline float blockReduceSum256(float v, volatile float* s4) {
#pragma unroll
  for (int o = 32; o > 0; o >>= 1) v += __shfl_down(v, o);
  __syncthreads();
  if ((threadIdx.x & 63) == 0) s4[threadIdx.x >> 6] = v;
  __syncthreads();
  return s4[0] + s4[1] + s4[2] + s4[3];
}

// ---------------- KP0: prep tables + FUSED k4 GF(2) row reduce (blocks >= 2048) ----
__global__ __launch_bounds__(256) void kP0_prep(const float* __restrict__ V,
                                                const float* __restrict__ U,
                                                const float* __restrict__ xin,
                                                const float* __restrict__ z_bias,
                                                ushort* __restrict__ Vbf,
                                                ushort* __restrict__ Vkpad2,
                                                ushort* __restrict__ Uhi,
                                                ushort* __restrict__ Ulo,
                                                ushort* __restrict__ xinbf,
                                                float* __restrict__ baseq,
                                                float* __restrict__ d_lpz,
                                                float* __restrict__ basepz,
                                                ull* __restrict__ Ct,
                                                uint32_t* __restrict__ bpmask,
                                                uint32_t kA0, uint32_t kA1,
                                                uint32_t kb0, uint32_t kb1) {
  __shared__ float red[4];
  __shared__ uint32_t Aw[NK][8];
  __shared__ uint32_t bbsh[NK];
  int tid = threadIdx.x;
  if (blockIdx.x >= NX * NZ / 256) {
    // ---- k4 body: GF(2) row reduce for t = blockIdx.x - 2048 ----
    int t = blockIdx.x - NX * NZ / 256;
    if (tid < NK * 8) {
      int r = tid >> 3, c = tid & 7;
      const uint32_t hA = (uint32_t)NT * NK * NZ / 2;
      uint32_t base_i = (uint32_t)(t * NK + r) * NZ + c * 32;
      uint32_t w = 0;
      for (int zz = 0; zz < 32; ++zz) {
        uint32_t rr = tf_select(kA0, kA1, base_i + zz, hA);
        w |= ((rr >> 31) ^ 1u) << zz;  // bit=1 iff u<0.5 (top bit 0)
      }
      Aw[r][c] = w;
    }
    if (tid < NK) {
      const uint32_t hb = (uint32_t)NT * NK / 2;
      uint32_t rb = tf_select(kb0, kb1, (uint32_t)(t * NK + tid), hb);
      bbsh[tid] = (rb >> 31) ^ 1u;
    }
    __syncthreads();
    if (tid >= 64) return;  // wave 0 does the elimination
    int lane = tid;
    ull w0 = 0, w1 = 0, w2 = 0, w3 = 0;
    uint32_t bbit = 0;
    if (lane < NK) {
      w0 = (ull)Aw[lane][0] | ((ull)Aw[lane][1] << 32);
      w1 = (ull)Aw[lane][2] | ((ull)Aw[lane][3] << 32);
      w2 = (ull)Aw[lane][4] | ((ull)Aw[lane][5] << 32);
      w3 = (ull)Aw[lane][6] | ((ull)Aw[lane][7] << 32);
      bbit = bbsh[lane];
    }
    for (int i = 0; i < NK; ++i) {
      int mybit = (int)((w0 >> i) & 1ull);
      ull mask = __ballot(lane < NK && mybit);
      ull cand = mask & (~0ull << i);
      int p = cand ? __builtin_ctzll(cand) : (NK - 1);
      int srcl = (lane == i) ? p : ((lane == p) ? i : lane);
      w0 = __shfl(w0, srcl); w1 = __shfl(w1, srcl); w2 = __shfl(w2, srcl); w3 = __shfl(w3, srcl);
      bbit = __shfl(bbit, srcl);
      ull p0 = __shfl(w0, i), p1 = __shfl(w1, i), p2 = __shfl(w2, i), p3 = __shfl(w3, i);
      uint32_t pvb = __shfl(bbit, i);
      int nb2 = (int)((w0 >> i) & 1ull);
      if (lane < NK && lane != i && nb2) {
        w0 ^= p0; w1 ^= p1; w2 ^= p2; w3 ^= p3; bbit ^= pvb;
      }
    }
    if (lane < NK) {
      w0 &= ~((1ull << NK) - 1ull);  // only columns z>=k feed proj
      ull* dstp = Ct + (size_t)(t * NK + lane) * 4;
      dstp[0] = w0; dstp[1] = w1; dstp[2] = w2; dstp[3] = w3;
    }
    ull bm = __ballot(lane < NK && bbit);
    if (lane == 0) bpmask[t] = (uint32_t)bm & 0x1FFFFFFu;
    return;
  }
  int e = blockIdx.x * 256 + tid;  // < NX*NZ = 524288
  {  // V
    int x = e >> 8, k = e & 255;
    float v = V[e];
    Vbf[e] = f2bf(v);
    if (k < 32) Vkpad2[x * 32 + k] = (k < NK) ? f2bf(v * LOG2E) : (ushort)0;
  }
  {  // U split hi/lo (U is [NZ][NX], 524288 elements)
    float u = U[e];
    ushort hi = f2bf(u);
    Uhi[e] = hi;
    float hv = __uint_as_float((uint32_t)hi << 16);
    Ulo[e] = f2bf(u - hv);
  }
  {  // xin cast (1048576 elements, 2 per thread)
    xinbf[e] = (xin[e] > 0.5f) ? (ushort)0x3F80 : (ushort)0;
    int e2 = e + NX * NZ;
    xinbf[e2] = (xin[e2] > 0.5f) ? (ushort)0x3F80 : (ushort)0;
  }
  if (e < NB) baseq[e] = 0.0f;
  if (blockIdx.x == 0) {
    int z = tid;
    float pz = sigclip(z_bias[z]);
    float lp = __logf(pz), l1 = __logf(1.0f - pz);
    d_lpz[z] = lp - l1;
    float s = blockReduceSum256(l1, red);
    if (z == 0) *basepz = s;
  }
}

// ---------------- K1W: fused q-GEMM (blocks 0..511) + W signdot (blocks 512..1023) --
__global__ __launch_bounds__(256) void k1w_mfma(const ushort* __restrict__ xinbf,
                                                const ushort* __restrict__ Uhi,
                                                const ushort* __restrict__ Ulo,
                                                const float* __restrict__ z_bias,
                                                const float* __restrict__ xin,
                                                const ushort* __restrict__ Vkpad2,
                                                float* __restrict__ outq,
                                                float* __restrict__ d_lq,
                                                float* __restrict__ baseq,
                                                float* __restrict__ W) {
  __shared__ float red[4][16][17];
  __shared__ float wred[4][NK];
  int tid = threadIdx.x;
  if (blockIdx.x < 512) {
    // ---- k1a body: q-GEMM via MFMA hi/lo split-K (exact to ~fp32) ----
    int wave = tid >> 6, lane = tid & 63, grp = lane >> 4, col = lane & 15;
    int b0 = (blockIdx.x >> 4) * 16;
    int z0 = (blockIdx.x & 15) * 16;
    f32x4 acc = {0.f, 0.f, 0.f, 0.f};
    const ushort* arow = xinbf + (size_t)(b0 + col) * NX + wave * 512 + grp * 8;
    const ushort* bhr = Uhi + (size_t)(z0 + col) * NX + wave * 512 + grp * 8;
    const ushort* blr = Ulo + (size_t)(z0 + col) * NX + wave * 512 + grp * 8;
#pragma unroll 4
    for (int s = 0; s < 16; ++s) {
      bf16x8 a = *(const bf16x8*)(arow + s * 32);
      bf16x8 bh = *(const bf16x8*)(bhr + s * 32);
      bf16x8 bl = *(const bf16x8*)(blr + s * 32);
      acc = __builtin_amdgcn_mfma_f32_16x16x32_bf16(a, bh, acc, 0, 0, 0);
      acc = __builtin_amdgcn_mfma_f32_16x16x32_bf16(a, bl, acc, 0, 0, 0);
    }
#pragma unroll
    for (int r = 0; r < 4; ++r) red[wave][grp * 4 + r][col] = acc[r];
    __syncthreads();
    int bi = tid >> 4, zi = tid & 15;
    float aa = red[0][bi][zi] + red[1][bi][zi] + red[2][bi][zi] + red[3][bi][zi] + z_bias[z0 + zi];
    int b = b0 + bi, z = z0 + zi;
    float q = sigclip(aa);
    outq[b * NZ + z] = q;
    float lq = __logf(q), l1 = __logf(1.0f - q);
    d_lq[b * NZ + z] = lq - l1;
    float s1 = l1;
#pragma unroll
    for (int o = 1; o < 16; o <<= 1) s1 += __shfl_xor(s1, o);
    if (zi == 0) atomicAdd(&baseq[b], s1);
    return;
  }
  // ---- kW body: W[b][k] = sum_x (1-2*xin[b,x]) * bf16val(Vkpad2[x,k]) ----
  int b = blockIdx.x - 512;
  float acc[NK];
#pragma unroll
  for (int j = 0; j < NK; ++j) acc[j] = 0.0f;
#pragma unroll
  for (int i = 0; i < 8; ++i) {
    int x = i * 256 + tid;
    float s = 1.0f - 2.0f * xin[(size_t)b * NX + x];
    const uint4* vp = (const uint4*)(Vkpad2 + (size_t)x * 32);
    uint4 q0 = vp[0], q1 = vp[1], q2 = vp[2], q3 = vp[3];
    uint32_t w[16] = {q0.x, q0.y, q0.z, q0.w, q1.x, q1.y, q1.z, q1.w,
                      q2.x, q2.y, q2.z, q2.w, q3.x, q3.y, q3.z, q3.w};
#pragma unroll
    for (int j = 0; j < NK; ++j) {
      uint32_t wd = w[j >> 1];
      float v = __uint_as_float((j & 1) ? (wd & 0xFFFF0000u) : (wd << 16));
      acc[j] = fmaf(s, v, acc[j]);
    }
  }
#pragma unroll
  for (int j = 0; j < NK; ++j) {
#pragma unroll
    for (int o = 1; o < 64; o <<= 1) acc[j] += __shfl_xor(acc[j], o);
  }
  if ((tid & 63) == 0) {
#pragma unroll
    for (int j = 0; j < NK; ++j) wred[tid >> 6][j] = acc[j];
  }
  __syncthreads();
  if (tid < NK) W[b * 32 + tid] = wred[0][tid] + wred[1][tid] + wred[2][tid] + wred[3][tid];
}

// ---------------- K2: samples + packed bits + tails + FUSED proj/Syd (was K5) -----
__global__ __launch_bounds__(256) void k2_samples(const float* __restrict__ q,
                                                  const float* __restrict__ d_lq,
                                                  const float* __restrict__ d_lpz,
                                                  const ull* __restrict__ Ct,
                                                  const uint32_t* __restrict__ bpmask,
                                                  const float* __restrict__ W,
                                                  float* __restrict__ samp_out,
                                                  ushort* __restrict__ samp16,
                                                  ull* __restrict__ Spack,
                                                  float* __restrict__ qtail,
                                                  float* __restrict__ ptail,
                                                  uint32_t* __restrict__ projb,
                                                  float* __restrict__ Syd,
                                                  uint32_t kz0, uint32_t kz1) {
  __shared__ float red[4];
  __shared__ ull sp_sh[4];
  int sb = blockIdx.x;
  int z = threadIdx.x;
  int b = sb & (NB - 1);
  uint32_t i = (uint32_t)sb * NZ + z;
  const uint32_t h = (uint32_t)SBTOT * NZ / 2;
  float u = tf_uniform(kz0, kz1, i, h);
  float qv = q[b * NZ + z];
  int smp = (u < qv) ? 1 : 0;
  samp_out[i] = (float)smp;
  samp16[i] = smp ? (ushort)0x3F80 : (ushort)0;
  ull m = __ballot(smp);
  if ((z & 63) == 0) { Spack[sb * 4 + (z >> 6)] = m; sp_sh[z >> 6] = m; }
  float dq = (z >= NK && smp) ? d_lq[b * NZ + z] : 0.0f;
  float dp = (z >= NK && smp) ? d_lpz[z] : 0.0f;
  float sq = blockReduceSum256(dq, red);  // syncthreads inside publish sp_sh
  float sp = blockReduceSum256(dp, red);
  if (z == 0) { qtail[sb] = sq; ptail[sb] = sp; }
  // ---- fused k5: threads 0..31 compute projb/Syd for this sb ----
  if (z < 32) {
    int t = z;
    ull s0 = sp_sh[0], s1 = sp_sh[1], s2 = sp_sh[2], s3 = sp_sh[3];
    uint32_t s25 = (uint32_t)(s0 & 0x1FFFFFFull);
    const float* Wb = W + (size_t)b * 32;
    uint32_t out;
    float syd = 0.0f;
    if (t < NT) {
      uint32_t bp = bpmask[t];
      uint32_t pb = 0;
#pragma unroll
      for (int j = 0; j < NK; ++j) {
        const ull* C = Ct + (size_t)(t * NK + j) * 4;
        int par = __popcll(s0 & C[0]) + __popcll(s1 & C[1]) + __popcll(s2 & C[2]) + __popcll(s3 & C[3]);
        uint32_t bit = ((uint32_t)(par ^ (int)(bp >> j))) & 1u;
        pb |= bit << j;
        int d = (int)bit - (int)((s25 >> j) & 1u);
        syd = fmaf((float)d, Wb[j], syd);
      }
      out = pb;
    } else {
      out = s25;  // d = pb - s25 = 0
    }
    projb[sb * 32 + t] = out;
    Syd[sb * 32 + t] = syd;
  }
}

// ---------------- K3M: bf16 MFMA GEMM (operand-swapped): C[x][sb] = V·samp^T ------
// Block covers x-tile of 128 and PAIRED sb rows {sb0..sb0+31} u {sb0+2560..sb0+2591}
// (pair (sb, sb+SBTOT/2) shares one threefry-2x32 hash: o0/o1). Epilogue stages
// f32 logits through LDS so global stores are fully coalesced.
__global__ __launch_bounds__(256) void k3m_gemm(const ushort* __restrict__ samp16,
                                                const ushort* __restrict__ Vbf,
                                                const float* __restrict__ x_bias,
                                                ushort* __restrict__ base2,
                                                float* __restrict__ ps_out,
                                                float* __restrict__ xo_out,
                                                uint32_t kx0, uint32_t kx1) {
  // Aliased LDS: GEMM staging As(8KB)+Bs(4KB); epilogue 2 tiles [16][132] f32.
  __shared__ __align__(16) char smem[2 * 2112 * 4];  // 16896 B
  ushort* As = (ushort*)smem;          // V rows (x)     128*32 bf16
  ushort* Bs = (ushort*)(smem + 8192); // samp rows (sb)  64*32 bf16
  float* Tt = (float*)smem;            // epilogue tiles

  int tid = threadIdx.x;
  int wave = tid >> 6, lane = tid & 63, grp = lane >> 4, col = lane & 15;
  int x0 = blockIdx.x * 128;
  int sb0 = blockIdx.y * 32;  // first-half base; pair rows at sb0 + SBTOT/2
  f32x4 acc[2][4];
#pragma unroll
  for (int mi = 0; mi < 2; ++mi)
#pragma unroll
    for (int ni = 0; ni < 4; ++ni) acc[mi][ni] = (f32x4){0.f, 0.f, 0.f, 0.f};

  for (int k0 = 0; k0 < NZ; k0 += 32) {
    {
      int rowb = tid >> 2, kcb = (tid & 3) << 3;
      int sbrow = (rowb < 32) ? (sb0 + rowb) : (sb0 + 2528 + rowb);  // 2560+(rowb-32)
      *(uint4*)&Bs[rowb * 32 + kcb] = *(const uint4*)&samp16[(size_t)sbrow * NZ + k0 + kcb];
#pragma unroll
      for (int c = tid; c < 512; c += 256) {
        int rowa = c >> 2, kca = (c & 3) << 3;
        *(uint4*)&As[rowa * 32 + kca] = *(const uint4*)&Vbf[(size_t)(x0 + rowa) * NZ + k0 + kca];
      }
    }
    __syncthreads();
    bf16x8 af[2], bfv[4];
#pragma unroll
    for (int mi = 0; mi < 2; ++mi)
      af[mi] = *(const bf16x8*)&As[(wave * 32 + mi * 16 + col) * 32 + grp * 8];
#pragma unroll
    for (int ni = 0; ni < 4; ++ni)
      bfv[ni] = *(const bf16x8*)&Bs[(ni * 16 + col) * 32 + grp * 8];
#pragma unroll
    for (int mi = 0; mi < 2; ++mi)
#pragma unroll
      for (int ni = 0; ni < 4; ++ni)
        acc[mi][ni] = __builtin_amdgcn_mfma_f32_16x16x32_bf16(af[mi], bfv[ni], acc[mi][ni], 0, 0, 0);
    __syncthreads();
  }

  // ---- epilogue: LDS transpose for coalesced stores + paired threefry ----
  const uint32_t HH = (uint32_t)(SBTOT / 2) * (uint32_t)NX;  // 5242880
#pragma unroll
  for (int pi = 0; pi < 2; ++pi) {
    __syncthreads();  // previous reads of smem complete
#pragma unroll
    for (int mi = 0; mi < 2; ++mi) {
      int cbase = wave * 32 + mi * 16 + grp * 4;
      *(float4*)&Tt[col * 132 + cbase] = *(float4*)&acc[mi][pi];          // sb_a tile
      *(float4*)&Tt[2112 + col * 132 + cbase] = *(float4*)&acc[mi][pi + 2];  // sb_b tile
    }
    __syncthreads();
#pragma unroll
    for (int pass = 0; pass < 2; ++pass) {
      int r = pass * 8 + (tid >> 5);   // sb-local row 0..15
      int c = (tid & 31) * 4;          // x-local col, float4 granularity
      float4 t0 = *(float4*)&Tt[r * 132 + c];
      float4 t1 = *(float4*)&Tt[2112 + r * 132 + c];
      float4 xb4 = *(const float4*)(x_bias + x0 + c);
      int sb_a = sb0 + pi * 16 + r;                 // < SBTOT/2
      size_t off_a = (size_t)sb_a * NX + x0 + c;
      size_t off_b = off_a + (size_t)HH;
      float a0 = t0.x + xb4.x, a1 = t0.y + xb4.y, a2 = t0.z + xb4.z, a3 = t0.w + xb4.w;
      float b0 = t1.x + xb4.x, b1 = t1.y + xb4.y, b2 = t1.z + xb4.z, b3 = t1.w + xb4.w;
      uint2 bpa, bpb;
      bpa.x = (uint32_t)f2bf(a0 * LOG2E) | ((uint32_t)f2bf(a1 * LOG2E) << 16);
      bpa.y = (uint32_t)f2bf(a2 * LOG2E) | ((uint32_t)f2bf(a3 * LOG2E) << 16);
      bpb.x = (uint32_t)f2bf(b0 * LOG2E) | ((uint32_t)f2bf(b1 * LOG2E) << 16);
      bpb.y = (uint32_t)f2bf(b2 * LOG2E) | ((uint32_t)f2bf(b3 * LOG2E) << 16);
      *(uint2*)(base2 + off_a) = bpa;
      *(uint2*)(base2 + off_b) = bpb;
      float4 pva = make_float4(sigclip(a0), sigclip(a1), sigclip(a2), sigclip(a3));
      float4 pvb = make_float4(sigclip(b0), sigclip(b1), sigclip(b2), sigclip(b3));
      *(float4*)(ps_out + off_a) = pva;
      *(float4*)(ps_out + off_b) = pvb;
      // one threefry per paired element: x0=fi (first half), x1=fi+HH (second half)
      uint32_t fi = (uint32_t)off_a;
      uint32_t r0, r1;
      float4 xva, xvb;
      tf2x32(kx0, kx1, fi + 0u, fi + 0u + HH, r0, r1);
      xva.x = ((__uint_as_float(0x3f800000u | (r0 >> 9)) - 1.0f) < pva.x) ? 1.0f : 0.0f;
      xvb.x = ((__uint_as_float(0x3f800000u | (r1 >> 9)) - 1.0f) < pvb.x) ? 1.0f : 0.0f;
      tf2x32(kx0, kx1, fi + 1u, fi + 1u + HH, r0, r1);
      xva.y = ((__uint_as_float(0x3f800000u | (r0 >> 9)) - 1.0f) < pva.y) ? 1.0f : 0.0f;
      xvb.y = ((__uint_as_float(0x3f800000u | (r1 >> 9)) - 1.0f) < pvb.y) ? 1.0f : 0.0f;
      tf2x32(kx0, kx1, fi + 2u, fi + 2u + HH, r0, r1);
      xva.z = ((__uint_as_float(0x3f800000u | (r0 >> 9)) - 1.0f) < pva.z) ? 1.0f : 0.0f;
      xvb.z = ((__uint_as_float(0x3f800000u | (r1 >> 9)) - 1.0f) < pvb.z) ? 1.0f : 0.0f;
      tf2x32(kx0, kx1, fi + 3u, fi + 3u + HH, r0, r1);
      xva.w = ((__uint_as_float(0x3f800000u | (r0 >> 9)) - 1.0f) < pva.w) ? 1.0f : 0.0f;
      xvb.w = ((__uint_as_float(0x3f800000u | (r1 >> 9)) - 1.0f) < pvb.w) ? 1.0f : 0.0f;
      *(float4*)(xo_out + off_a) = xva;
      *(float4*)(xo_out + off_b) = xvb;
    }
  }
}

// ---------------- K6: logp_x via MFMA delta-GEMM + fused softplus (log2-space) ----------
// (reverted to the proven low-VGPR form: 28 VGPR, occupancy ~70%)
__global__ __launch_bounds__(256) void k6_mfma(const ushort* __restrict__ base2,
                                               const ushort* __restrict__ Vkpad2,
                                               const float* __restrict__ xin,
                                               const uint32_t* __restrict__ projb,
                                               const ull* __restrict__ Spack,
                                               const float* __restrict__ Syd,
                                               float* __restrict__ logpx) {
  __shared__ float bvsm[NX];  // b2 per x — 8 KB
  __shared__ float lsum[4][32];
  __shared__ float red[4];
  int sb = blockIdx.x;
  int b = sb & (NB - 1);
  int tid = threadIdx.x;
  int wave = tid >> 6, lane = tid & 63;
  int grp = lane >> 4, col = lane & 15;
  // stage base2 row (bf16 -> f32) + analytic sum_x s*b2
  const uint4* b16p = (const uint4*)(base2 + (size_t)sb * NX);
  const float4* x4p = (const float4*)(xin + (size_t)b * NX);
  float sbacc = 0.0f;
  {
    uint4 bu = b16p[tid];
    float4 xv0 = x4p[tid * 2], xv1 = x4p[tid * 2 + 1];
    uint32_t wds[4] = {bu.x, bu.y, bu.z, bu.w};
    float bv[8];
#pragma unroll
    for (int j = 0; j < 8; ++j) {
      uint32_t wd = wds[j >> 1];
      bv[j] = __uint_as_float((j & 1) ? (wd & 0xFFFF0000u) : (wd << 16));
    }
    float sg[8] = {1.0f - 2.0f * xv0.x, 1.0f - 2.0f * xv0.y, 1.0f - 2.0f * xv0.z,
                   1.0f - 2.0f * xv0.w, 1.0f - 2.0f * xv1.x, 1.0f - 2.0f * xv1.y,
                   1.0f - 2.0f * xv1.z, 1.0f - 2.0f * xv1.w};
#pragma unroll
    for (int j = 0; j < 8; ++j) {
      bvsm[tid * 8 + j] = bv[j];
      sbacc = fmaf(sg[j], bv[j], sbacc);
    }
  }
  float Sb = blockReduceSum256(sbacc, red);  // includes syncthreads (guards bvsm)
  // A-frags: lane holds m=col (t within tile), k = grp*8+j
  uint32_t s25 = (uint32_t)(Spack[sb * 4] & 0x1FFFFFFull);
  uint32_t pb0 = projb[sb * 32 + col];
  uint32_t pb1 = projb[sb * 32 + 16 + col];
  bf16x8 a0, a1;
  union { ushort u; __bf16 hh; } cvt;
#pragma unroll
  for (int j = 0; j < 8; ++j) {
    int k = grp * 8 + j;
    int sbit = (int)((s25 >> k) & 1u);
    int d0 = (int)((pb0 >> k) & 1u) - sbit;
    int d1 = (int)((pb1 >> k) & 1u) - sbit;
    cvt.u = (ushort)(d0 == 0 ? 0 : (d0 > 0 ? 0x3F80 : 0xBF80)); a0[j] = cvt.hh;
    cvt.u = (ushort)(d1 == 0 ? 0 : (d1 > 0 ? 0x3F80 : 0xBF80)); a1[j] = cvt.hh;
  }
  float acca[8], pp[8];
#pragma unroll
  for (int r = 0; r < 8; ++r) { acca[r] = 0.0f; pp[r] = 1.0f; }
  const ushort* vkbase = Vkpad2 + (size_t)(wave * 512 + col) * 32 + grp * 8;
#pragma unroll 4
  for (int i = 0; i < 32; ++i) {
    int x = (wave * 32 + i) * 16 + col;
    bf16x8 bfr = *(const bf16x8*)(vkbase + (size_t)i * 16 * 32);
    f32x4 c0 = {0.f, 0.f, 0.f, 0.f}, c1 = {0.f, 0.f, 0.f, 0.f};
    c0 = __builtin_amdgcn_mfma_f32_16x16x32_bf16(a0, bfr, c0, 0, 0, 0);
    c1 = __builtin_amdgcn_mfma_f32_16x16x32_bf16(a1, bfr, c1, 0, 0, 0);
    float bs = bvsm[x];
#pragma unroll
    for (int r = 0; r < 4; ++r) {
      float y0 = bs + c0[r];
      acca[r] += fabsf(y0);
      pp[r] = fmaf(pp[r], __builtin_amdgcn_exp2f(-fabsf(y0)), pp[r]);
      float y1 = bs + c1[r];
      acca[4 + r] += fabsf(y1);
      pp[4 + r] = fmaf(pp[4 + r], __builtin_amdgcn_exp2f(-fabsf(y1)), pp[4 + r]);
    }
  }
#pragma unroll
  for (int r = 0; r < 8; ++r) {
    float m = 0.5f * acca[r] + __log2f(pp[r]);
#pragma unroll
    for (int off = 1; off < 16; off <<= 1) m += __shfl_xor(m, off);
    if (col == 0) {
      int t = (r < 4) ? (grp * 4 + r) : (16 + grp * 4 + (r - 4));
      lsum[wave][t] = m;
    }
  }
  __syncthreads();
  if (tid < NT) {
    float tot = lsum[0][tid] + lsum[1][tid] + lsum[2][tid] + lsum[3][tid];
    tot += 0.5f * (Sb + Syd[sb * 32 + tid]);
    logpx[(size_t)tid * SBTOT + sb] = -LN2 * tot;
  }
}

// ---------------- K7: per-t weighted reduction, split over 8 b-chunks ----------------
__global__ __launch_bounds__(64) void k7_reduce(const float* __restrict__ logpx,
                                                const uint32_t* __restrict__ projb,
                                                const float* __restrict__ qtail,
                                                const float* __restrict__ ptail,
                                                const float* __restrict__ baseq,
                                                const float* __restrict__ d_lq,
                                                const float* __restrict__ d_lpz,
                                                const float* __restrict__ basepz,
                                                double* __restrict__ pelbo_part) {
  int t = blockIdx.x;
  int chunk = blockIdx.y;
  int lane = threadIdx.x;
  int b = chunk * 64 + lane;
  float dlq[NK];
#pragma unroll
  for (int j = 0; j < NK; ++j) dlq[j] = d_lq[b * NZ + j];
  float bq = baseq[b];
  float bpz = *basepz;
  float lq[NS], lp[NS];
#pragma unroll
  for (int s = 0; s < NS; ++s) {
    int sb = s * NB + b;
    uint32_t m = projb[sb * 32 + t];
    float sq = 0.0f, spv = 0.0f;
#pragma unroll
    for (int j = 0; j < NK; ++j) {
      float on = (float)((m >> j) & 1u);
      sq += on * dlq[j];
      spv += on * d_lpz[j];
    }
    lq[s] = bq + qtail[sb] + sq;
    lp[s] = logpx[t * SBTOT + sb] + bpz + ptail[sb] + spv;
  }
  float mx = lq[0];
#pragma unroll
  for (int s = 1; s < NS; ++s) mx = fmaxf(mx, lq[s]);
  float den = 0.0f, num = 0.0f;
#pragma unroll
  for (int s = 0; s < NS; ++s) {
    float w = __expf(lq[s] - mx);
    den += w;
    num += w * (lq[s] - lp[s]);
  }
  double v = (double)(num / den);
#pragma unroll
  for (int o = 32; o > 0; o >>= 1) v += __shfl_down(v, o);
  if (lane == 0) pelbo_part[t * 8 + chunk] = v;
}

// ---------------- K8: final loss (sum 8 parts per t, mean over t) ----------------
__global__ __launch_bounds__(64) void k8_loss(const double* __restrict__ pelbo_part,
                                              float* __restrict__ out_loss) {
  int t = threadIdx.x;
  double v = 0.0;
  if (t < NT) {
#pragma unroll
    for (int c = 0; c < 8; ++c) v += pelbo_part[t * 8 + c];
  }
#pragma unroll
  for (int o = 32; o > 0; o >>= 1) v += __shfl_down(v, o);
  if (t == 0) *out_loss = (float)(v / (double)NT);
}

extern "C" void kernel_launch(void* const* d_in, const int* in_sizes, int n_in,
                              void* d_out, int out_size, void* d_ws, size_t ws_size,
                              hipStream_t stream) {
  const float* xin = (const float*)d_in[0];
  const float* U = (const float*)d_in[1];
  const float* V = (const float*)d_in[2];
  const float* x_bias = (const float*)d_in[3];
  const float* z_bias = (const float*)d_in[4];
  float* out = (float*)d_out;

  char* p = (char*)d_ws;
  ushort* base2 = (ushort*)p;             p += (size_t)SBTOT * NX * 2;
  float* d_lq = (float*)p;                p += (size_t)NB * NZ * 4;
  float* baseq = (float*)p;               p += (size_t)NB * 4;
  float* d_lpz = (float*)p;               p += (size_t)NZ * 4;
  float* basepz = (float*)p;              p += 16;
  ull* Spack = (ull*)p;                   p += (size_t)SBTOT * 4 * 8;
  float* qtail = (float*)p;               p += (size_t)SBTOT * 4;
  float* ptail = (float*)p;               p += (size_t)SBTOT * 4;
  ull* Ct = (ull*)p;                      p += (size_t)NT * NK * 4 * 8;
  uint32_t* bpm = (uint32_t*)p;           p += 128;
  uint32_t* projb = (uint32_t*)p;         p += (size_t)SBTOT * 32 * 4;
  float* Syd = (float*)p;                 p += (size_t)SBTOT * 32 * 4;
  float* logpx = (float*)p;               p += (size_t)NT * SBTOT * 4;
  double* pelbo = (double*)p;             p += (size_t)NT * 8 * 8;
  ushort* Vkpad2 = (ushort*)p;            p += (size_t)NX * 32 * 2;
  ushort* Vbf = (ushort*)p;               p += (size_t)NX * NZ * 2;
  ushort* samp16 = (ushort*)p;            p += (size_t)SBTOT * NZ * 2;
  float* W = (float*)p;                   p += (size_t)NB * 32 * 4;
  ushort* Uhi = (ushort*)p;               p += (size_t)NZ * NX * 2;
  ushort* Ulo = (ushort*)p;               p += (size_t)NZ * NX * 2;
  ushort* xinbf = (ushort*)p;             p += (size_t)NB * NX * 2;
  (void)ws_size; (void)in_sizes; (void)n_in; (void)out_size;

  // JAX: key(42) -> split 4 -> kz,kx,kA,kb
  uint32_t o0[4], o1[4];
  for (int j = 0; j < 4; ++j) tf2x32(0u, 42u, (uint32_t)j, (uint32_t)(4 + j), o0[j], o1[j]);
  uint32_t kz0 = o0[0], kz1 = o0[1];
  uint32_t kx0 = o0[2], kx1 = o0[3];
  uint32_t kA0 = o1[0], kA1 = o1[1];
  uint32_t kb0 = o1[2], kb1 = o1[3];

  kP0_prep<<<NX * NZ / 256 + NT, 256, 0, stream>>>(V, U, xin, z_bias, Vbf, Vkpad2,
                                                   Uhi, Ulo, xinbf, baseq, d_lpz, basepz,
                                                   Ct, bpm, kA0, kA1, kb0, kb1);
  k1w_mfma<<<1024, 256, 0, stream>>>(xinbf, Uhi, Ulo, z_bias, xin, Vkpad2,
                                     out + OFF_Q, d_lq, baseq, W);
  k2_samples<<<SBTOT, 256, 0, stream>>>(out + OFF_Q, d_lq, d_lpz, Ct, bpm, W,
                                        out + OFF_SAMP, samp16, Spack, qtail, ptail,
                                        projb, Syd, kz0, kz1);
  dim3 g3(NX / 128, SBTOT / 64);
  k3m_gemm<<<g3, 256, 0, stream>>>(samp16, Vbf, x_bias, base2,
                                   out + OFF_PS, out + OFF_XO, kx0, kx1);
  k6_mfma<<<SBTOT, 256, 0, stream>>>(base2, Vkpad2, xin, projb, Spack, Syd, logpx);
  dim3 g7(NT, 8);
  k7_reduce<<<g7, 64, 0, stream>>>(logpx, projb, qtail, ptail, baseq, d_lq,
                                   d_lpz, basepz, pelbo);
  k8_loss<<<1, 64, 0, stream>>>(pelbo, out + OFF_LOSS);
}

// Round 5
// 256.694 us; speedup vs baseline: 1.0517x; 1.0054x over previous
//
#include <hip/hip_runtime.h>
#include <cstdint>

// Problem constants (setup_inputs fixed: nx=2048, nz=256, B=512, S=10, k=25, T=30)
#define NX 2048
#define NZ 256
#define NB 512
#define NS 10
#define NK 25
#define NT 30
#define SBTOT (NS * NB)  // 5120

#define LOG2E 1.4426950408889634f
#define LN2 0.6931471805599453f

// d_out flat layout (all float32): q, samples_z, ps, xouts, loss
#define OFF_Q 0
#define OFF_SAMP (NB * NZ)
#define OFF_PS (OFF_SAMP + SBTOT * NZ)
#define OFF_XO (OFF_PS + SBTOT * NX)
#define OFF_LOSS (OFF_XO + SBTOT * NX)

typedef unsigned long long ull;
typedef __bf16 bf16x8 __attribute__((ext_vector_type(8)));
typedef float f32x4 __attribute__((ext_vector_type(4)));
typedef uint32_t u32x2 __attribute__((ext_vector_type(2)));

// ---------------- JAX Threefry-2x32 (exact) ----------------
__host__ __device__ inline void tf2x32(uint32_t k0, uint32_t k1, uint32_t x0, uint32_t x1,
                                       uint32_t& o0, uint32_t& o1) {
  uint32_t k2 = k0 ^ k1 ^ 0x1BD11BDAu;
  x0 += k0; x1 += k1;
#define TF_R(r) { x0 += x1; x1 = (x1 << (r)) | (x1 >> (32 - (r))); x1 ^= x0; }
  TF_R(13) TF_R(15) TF_R(26) TF_R(6)
  x0 += k1; x1 += k2 + 1u;
  TF_R(17) TF_R(29) TF_R(16) TF_R(24)
  x0 += k2; x1 += k0 + 2u;
  TF_R(13) TF_R(15) TF_R(26) TF_R(6)
  x0 += k0; x1 += k1 + 3u;
  TF_R(17) TF_R(29) TF_R(16) TF_R(24)
  x0 += k1; x1 += k2 + 4u;
  TF_R(13) TF_R(15) TF_R(26) TF_R(6)
  x0 += k2; x1 += k0 + 5u;
#undef TF_R
  o0 = x0; o1 = x1;
}

// JAX threefry over iota(n): element i (h=n/2): i<h -> o0(i,i+h); else o1(i-h,i)
__device__ inline uint32_t tf_select(uint32_t k0, uint32_t k1, uint32_t i, uint32_t h) {
  bool lo = i < h;
  uint32_t x0 = lo ? i : i - h;
  uint32_t x1 = lo ? i + h : i;
  uint32_t o0, o1;
  tf2x32(k0, k1, x0, x1, o0, o1);
  return lo ? o0 : o1;
}

__device__ inline float tf_uniform(uint32_t k0, uint32_t k1, uint32_t i, uint32_t h) {
  uint32_t r = tf_select(k0, k1, i, h);
  return __uint_as_float(0x3f800000u | (r >> 9)) - 1.0f;  // [0,1), exactly JAX
}

__device__ inline float sigclip(float a) {
  float p = 1.0f / (1.0f + __expf(-a));
  return fminf(fmaxf(p, 1e-6f), 1.0f - 1e-6f);
}

__device__ inline ushort f2bf(float f) {  // RNE f32->bf16 (no NaN inputs here)
  uint32_t u = __float_as_uint(f);
  return (ushort)((u + 0x7FFFu + ((u >> 16) & 1u)) >> 16);
}

__device__ inline float blockReduceSum256(float v, volatile float* s4) {
#pragma unroll
  for (int o = 32; o > 0; o >>= 1) v += __shfl_down(v, o);
  __syncthreads();
  if ((threadIdx.x & 63) == 0) s4[threadIdx.x >> 6] = v;
  __syncthreads();
  return s4[0] + s4[1] + s4[2] + s4[3];
}

// ---------------- KP0: prep tables + FUSED k4 GF(2) row reduce (blocks >= 2048) ----
__global__ __launch_bounds__(256) void kP0_prep(const float* __restrict__ V,
                                                const float* __restrict__ U,
                                                const float* __restrict__ xin,
                                                const float* __restrict__ z_bias,
                                                ushort* __restrict__ Vbf,
                                                ushort* __restrict__ Vkpad2,
                                                ushort* __restrict__ Uhi,
                                                ushort* __restrict__ Ulo,
                                                ushort* __restrict__ xinbf,
                                                float* __restrict__ baseq,
                                                float* __restrict__ d_lpz,
                                                float* __restrict__ basepz,
                                                ull* __restrict__ Ct,
                                                uint32_t* __restrict__ bpmask,
                                                uint32_t kA0, uint32_t kA1,
                                                uint32_t kb0, uint32_t kb1) {
  __shared__ float red[4];
  __shared__ uint32_t Aw[NK][8];
  __shared__ uint32_t bbsh[NK];
  int tid = threadIdx.x;
  if (blockIdx.x >= NX * NZ / 256) {
    // ---- k4 body: GF(2) row reduce for t = blockIdx.x - 2048 ----
    int t = blockIdx.x - NX * NZ / 256;
    if (tid < NK * 8) {
      int r = tid >> 3, c = tid & 7;
      const uint32_t hA = (uint32_t)NT * NK * NZ / 2;
      uint32_t base_i = (uint32_t)(t * NK + r) * NZ + c * 32;
      uint32_t w = 0;
      for (int zz = 0; zz < 32; ++zz) {
        uint32_t rr = tf_select(kA0, kA1, base_i + zz, hA);
        w |= ((rr >> 31) ^ 1u) << zz;  // bit=1 iff u<0.5 (top bit 0)
      }
      Aw[r][c] = w;
    }
    if (tid < NK) {
      const uint32_t hb = (uint32_t)NT * NK / 2;
      uint32_t rb = tf_select(kb0, kb1, (uint32_t)(t * NK + tid), hb);
      bbsh[tid] = (rb >> 31) ^ 1u;
    }
    __syncthreads();
    if (tid >= 64) return;  // wave 0 does the elimination
    int lane = tid;
    ull w0 = 0, w1 = 0, w2 = 0, w3 = 0;
    uint32_t bbit = 0;
    if (lane < NK) {
      w0 = (ull)Aw[lane][0] | ((ull)Aw[lane][1] << 32);
      w1 = (ull)Aw[lane][2] | ((ull)Aw[lane][3] << 32);
      w2 = (ull)Aw[lane][4] | ((ull)Aw[lane][5] << 32);
      w3 = (ull)Aw[lane][6] | ((ull)Aw[lane][7] << 32);
      bbit = bbsh[lane];
    }
    for (int i = 0; i < NK; ++i) {
      int mybit = (int)((w0 >> i) & 1ull);
      ull mask = __ballot(lane < NK && mybit);
      ull cand = mask & (~0ull << i);
      int p = cand ? __builtin_ctzll(cand) : (NK - 1);
      int srcl = (lane == i) ? p : ((lane == p) ? i : lane);
      w0 = __shfl(w0, srcl); w1 = __shfl(w1, srcl); w2 = __shfl(w2, srcl); w3 = __shfl(w3, srcl);
      bbit = __shfl(bbit, srcl);
      ull p0 = __shfl(w0, i), p1 = __shfl(w1, i), p2 = __shfl(w2, i), p3 = __shfl(w3, i);
      uint32_t pvb = __shfl(bbit, i);
      int nb2 = (int)((w0 >> i) & 1ull);
      if (lane < NK && lane != i && nb2) {
        w0 ^= p0; w1 ^= p1; w2 ^= p2; w3 ^= p3; bbit ^= pvb;
      }
    }
    if (lane < NK) {
      w0 &= ~((1ull << NK) - 1ull);  // only columns z>=k feed proj
      ull* dstp = Ct + (size_t)(t * NK + lane) * 4;
      dstp[0] = w0; dstp[1] = w1; dstp[2] = w2; dstp[3] = w3;
    }
    ull bm = __ballot(lane < NK && bbit);
    if (lane == 0) bpmask[t] = (uint32_t)bm & 0x1FFFFFFu;
    return;
  }
  int e = blockIdx.x * 256 + tid;  // < NX*NZ = 524288
  {  // V
    int x = e >> 8, k = e & 255;
    float v = V[e];
    Vbf[e] = f2bf(v);
    if (k < 32) Vkpad2[x * 32 + k] = (k < NK) ? f2bf(v * LOG2E) : (ushort)0;
  }
  {  // U split hi/lo (U is [NZ][NX], 524288 elements)
    float u = U[e];
    ushort hi = f2bf(u);
    Uhi[e] = hi;
    float hv = __uint_as_float((uint32_t)hi << 16);
    Ulo[e] = f2bf(u - hv);
  }
  {  // xin cast (1048576 elements, 2 per thread)
    xinbf[e] = (xin[e] > 0.5f) ? (ushort)0x3F80 : (ushort)0;
    int e2 = e + NX * NZ;
    xinbf[e2] = (xin[e2] > 0.5f) ? (ushort)0x3F80 : (ushort)0;
  }
  if (e < NB) baseq[e] = 0.0f;
  if (blockIdx.x == 0) {
    int z = tid;
    float pz = sigclip(z_bias[z]);
    float lp = __logf(pz), l1 = __logf(1.0f - pz);
    d_lpz[z] = lp - l1;
    float s = blockReduceSum256(l1, red);
    if (z == 0) *basepz = s;
  }
}

// ---------------- K1W: fused q-GEMM (blocks 0..511) + W signdot (blocks 512..1023) --
__global__ __launch_bounds__(256) void k1w_mfma(const ushort* __restrict__ xinbf,
                                                const ushort* __restrict__ Uhi,
                                                const ushort* __restrict__ Ulo,
                                                const float* __restrict__ z_bias,
                                                const float* __restrict__ xin,
                                                const ushort* __restrict__ Vkpad2,
                                                float* __restrict__ outq,
                                                float* __restrict__ d_lq,
                                                float* __restrict__ baseq,
                                                float* __restrict__ W) {
  __shared__ float red[4][16][17];
  __shared__ float wred[4][NK];
  int tid = threadIdx.x;
  if (blockIdx.x < 512) {
    // ---- k1a body: q-GEMM via MFMA hi/lo split-K (exact to ~fp32) ----
    int wave = tid >> 6, lane = tid & 63, grp = lane >> 4, col = lane & 15;
    int b0 = (blockIdx.x >> 4) * 16;
    int z0 = (blockIdx.x & 15) * 16;
    f32x4 acc = {0.f, 0.f, 0.f, 0.f};
    const ushort* arow = xinbf + (size_t)(b0 + col) * NX + wave * 512 + grp * 8;
    const ushort* bhr = Uhi + (size_t)(z0 + col) * NX + wave * 512 + grp * 8;
    const ushort* blr = Ulo + (size_t)(z0 + col) * NX + wave * 512 + grp * 8;
#pragma unroll 4
    for (int s = 0; s < 16; ++s) {
      bf16x8 a = *(const bf16x8*)(arow + s * 32);
      bf16x8 bh = *(const bf16x8*)(bhr + s * 32);
      bf16x8 bl = *(const bf16x8*)(blr + s * 32);
      acc = __builtin_amdgcn_mfma_f32_16x16x32_bf16(a, bh, acc, 0, 0, 0);
      acc = __builtin_amdgcn_mfma_f32_16x16x32_bf16(a, bl, acc, 0, 0, 0);
    }
#pragma unroll
    for (int r = 0; r < 4; ++r) red[wave][grp * 4 + r][col] = acc[r];
    __syncthreads();
    int bi = tid >> 4, zi = tid & 15;
    float aa = red[0][bi][zi] + red[1][bi][zi] + red[2][bi][zi] + red[3][bi][zi] + z_bias[z0 + zi];
    int b = b0 + bi, z = z0 + zi;
    float q = sigclip(aa);
    outq[b * NZ + z] = q;
    float lq = __logf(q), l1 = __logf(1.0f - q);
    d_lq[b * NZ + z] = lq - l1;
    float s1 = l1;
#pragma unroll
    for (int o = 1; o < 16; o <<= 1) s1 += __shfl_xor(s1, o);
    if (zi == 0) atomicAdd(&baseq[b], s1);
    return;
  }
  // ---- kW body: W[b][k] = sum_x (1-2*xin[b,x]) * bf16val(Vkpad2[x,k]) ----
  int b = blockIdx.x - 512;
  float acc[NK];
#pragma unroll
  for (int j = 0; j < NK; ++j) acc[j] = 0.0f;
#pragma unroll
  for (int i = 0; i < 8; ++i) {
    int x = i * 256 + tid;
    float s = 1.0f - 2.0f * xin[(size_t)b * NX + x];
    const uint4* vp = (const uint4*)(Vkpad2 + (size_t)x * 32);
    uint4 q0 = vp[0], q1 = vp[1], q2 = vp[2], q3 = vp[3];
    uint32_t w[16] = {q0.x, q0.y, q0.z, q0.w, q1.x, q1.y, q1.z, q1.w,
                      q2.x, q2.y, q2.z, q2.w, q3.x, q3.y, q3.z, q3.w};
#pragma unroll
    for (int j = 0; j < NK; ++j) {
      uint32_t wd = w[j >> 1];
      float v = __uint_as_float((j & 1) ? (wd & 0xFFFF0000u) : (wd << 16));
      acc[j] = fmaf(s, v, acc[j]);
    }
  }
#pragma unroll
  for (int j = 0; j < NK; ++j) {
#pragma unroll
    for (int o = 1; o < 64; o <<= 1) acc[j] += __shfl_xor(acc[j], o);
  }
  if ((tid & 63) == 0) {
#pragma unroll
    for (int j = 0; j < NK; ++j) wred[tid >> 6][j] = acc[j];
  }
  __syncthreads();
  if (tid < NK) W[b * 32 + tid] = wred[0][tid] + wred[1][tid] + wred[2][tid] + wred[3][tid];
}

// ---------------- K2: samples + packed bits + tails + FUSED proj/Syd (was K5) -----
__global__ __launch_bounds__(256) void k2_samples(const float* __restrict__ q,
                                                  const float* __restrict__ d_lq,
                                                  const float* __restrict__ d_lpz,
                                                  const ull* __restrict__ Ct,
                                                  const uint32_t* __restrict__ bpmask,
                                                  const float* __restrict__ W,
                                                  float* __restrict__ samp_out,
                                                  ushort* __restrict__ samp16,
                                                  ull* __restrict__ Spack,
                                                  float* __restrict__ qtail,
                                                  float* __restrict__ ptail,
                                                  uint32_t* __restrict__ projb,
                                                  float* __restrict__ Syd,
                                                  uint32_t kz0, uint32_t kz1) {
  __shared__ float red[4];
  __shared__ ull sp_sh[4];
  int sb = blockIdx.x;
  int z = threadIdx.x;
  int b = sb & (NB - 1);
  uint32_t i = (uint32_t)sb * NZ + z;
  const uint32_t h = (uint32_t)SBTOT * NZ / 2;
  float u = tf_uniform(kz0, kz1, i, h);
  float qv = q[b * NZ + z];
  int smp = (u < qv) ? 1 : 0;
  __builtin_nontemporal_store((float)smp, samp_out + i);  // pure output: stream
  samp16[i] = smp ? (ushort)0x3F80 : (ushort)0;
  ull m = __ballot(smp);
  if ((z & 63) == 0) { Spack[sb * 4 + (z >> 6)] = m; sp_sh[z >> 6] = m; }
  float dq = (z >= NK && smp) ? d_lq[b * NZ + z] : 0.0f;
  float dp = (z >= NK && smp) ? d_lpz[z] : 0.0f;
  float sq = blockReduceSum256(dq, red);  // syncthreads inside publish sp_sh
  float sp = blockReduceSum256(dp, red);
  if (z == 0) { qtail[sb] = sq; ptail[sb] = sp; }
  // ---- fused k5: threads 0..31 compute projb/Syd for this sb ----
  if (z < 32) {
    int t = z;
    ull s0 = sp_sh[0], s1 = sp_sh[1], s2 = sp_sh[2], s3 = sp_sh[3];
    uint32_t s25 = (uint32_t)(s0 & 0x1FFFFFFull);
    const float* Wb = W + (size_t)b * 32;
    uint32_t out;
    float syd = 0.0f;
    if (t < NT) {
      uint32_t bp = bpmask[t];
      uint32_t pb = 0;
#pragma unroll
      for (int j = 0; j < NK; ++j) {
        const ull* C = Ct + (size_t)(t * NK + j) * 4;
        int par = __popcll(s0 & C[0]) + __popcll(s1 & C[1]) + __popcll(s2 & C[2]) + __popcll(s3 & C[3]);
        uint32_t bit = ((uint32_t)(par ^ (int)(bp >> j))) & 1u;
        pb |= bit << j;
        int d = (int)bit - (int)((s25 >> j) & 1u);
        syd = fmaf((float)d, Wb[j], syd);
      }
      out = pb;
    } else {
      out = s25;  // d = pb - s25 = 0
    }
    projb[sb * 32 + t] = out;
    Syd[sb * 32 + t] = syd;
  }
}

// ---------------- K3M: bf16 MFMA GEMM (operand-swapped): C[x][sb] = V·samp^T ------
// Block covers x-tile of 128 and PAIRED sb rows {sb0..sb0+31} u {sb0+2560..sb0+2591}
// (pair (sb, sb+SBTOT/2) shares one threefry-2x32 hash: o0/o1). Epilogue stages
// f32 logits through LDS so global stores are fully coalesced. ps/xo use
// NON-TEMPORAL stores (pure outputs, never re-read on device) to avoid L2
// write-allocate thrash; base2 stays cached (re-read by k6).
__global__ __launch_bounds__(256) void k3m_gemm(const ushort* __restrict__ samp16,
                                                const ushort* __restrict__ Vbf,
                                                const float* __restrict__ x_bias,
                                                ushort* __restrict__ base2,
                                                float* __restrict__ ps_out,
                                                float* __restrict__ xo_out,
                                                uint32_t kx0, uint32_t kx1) {
  // Aliased LDS: GEMM staging As(8KB)+Bs(4KB); epilogue 2 tiles [16][132] f32.
  __shared__ __align__(16) char smem[2 * 2112 * 4];  // 16896 B
  ushort* As = (ushort*)smem;          // V rows (x)     128*32 bf16
  ushort* Bs = (ushort*)(smem + 8192); // samp rows (sb)  64*32 bf16
  float* Tt = (float*)smem;            // epilogue tiles

  int tid = threadIdx.x;
  int wave = tid >> 6, lane = tid & 63, grp = lane >> 4, col = lane & 15;
  int x0 = blockIdx.x * 128;
  int sb0 = blockIdx.y * 32;  // first-half base; pair rows at sb0 + SBTOT/2
  f32x4 acc[2][4];
#pragma unroll
  for (int mi = 0; mi < 2; ++mi)
#pragma unroll
    for (int ni = 0; ni < 4; ++ni) acc[mi][ni] = (f32x4){0.f, 0.f, 0.f, 0.f};

  for (int k0 = 0; k0 < NZ; k0 += 32) {
    {
      int rowb = tid >> 2, kcb = (tid & 3) << 3;
      int sbrow = (rowb < 32) ? (sb0 + rowb) : (sb0 + 2528 + rowb);  // 2560+(rowb-32)
      *(uint4*)&Bs[rowb * 32 + kcb] = *(const uint4*)&samp16[(size_t)sbrow * NZ + k0 + kcb];
#pragma unroll
      for (int c = tid; c < 512; c += 256) {
        int rowa = c >> 2, kca = (c & 3) << 3;
        *(uint4*)&As[rowa * 32 + kca] = *(const uint4*)&Vbf[(size_t)(x0 + rowa) * NZ + k0 + kca];
      }
    }
    __syncthreads();
    bf16x8 af[2], bfv[4];
#pragma unroll
    for (int mi = 0; mi < 2; ++mi)
      af[mi] = *(const bf16x8*)&As[(wave * 32 + mi * 16 + col) * 32 + grp * 8];
#pragma unroll
    for (int ni = 0; ni < 4; ++ni)
      bfv[ni] = *(const bf16x8*)&Bs[(ni * 16 + col) * 32 + grp * 8];
#pragma unroll
    for (int mi = 0; mi < 2; ++mi)
#pragma unroll
      for (int ni = 0; ni < 4; ++ni)
        acc[mi][ni] = __builtin_amdgcn_mfma_f32_16x16x32_bf16(af[mi], bfv[ni], acc[mi][ni], 0, 0, 0);
    __syncthreads();
  }

  // ---- epilogue: LDS transpose for coalesced stores + paired threefry ----
  const uint32_t HH = (uint32_t)(SBTOT / 2) * (uint32_t)NX;  // 5242880
#pragma unroll
  for (int pi = 0; pi < 2; ++pi) {
    __syncthreads();  // previous reads of smem complete
#pragma unroll
    for (int mi = 0; mi < 2; ++mi) {
      int cbase = wave * 32 + mi * 16 + grp * 4;
      *(float4*)&Tt[col * 132 + cbase] = *(float4*)&acc[mi][pi];          // sb_a tile
      *(float4*)&Tt[2112 + col * 132 + cbase] = *(float4*)&acc[mi][pi + 2];  // sb_b tile
    }
    __syncthreads();
#pragma unroll
    for (int pass = 0; pass < 2; ++pass) {
      int r = pass * 8 + (tid >> 5);   // sb-local row 0..15
      int c = (tid & 31) * 4;          // x-local col, float4 granularity
      float4 t0 = *(float4*)&Tt[r * 132 + c];
      float4 t1 = *(float4*)&Tt[2112 + r * 132 + c];
      float4 xb4 = *(const float4*)(x_bias + x0 + c);
      int sb_a = sb0 + pi * 16 + r;                 // < SBTOT/2
      size_t off_a = (size_t)sb_a * NX + x0 + c;
      size_t off_b = off_a + (size_t)HH;
      float a0 = t0.x + xb4.x, a1 = t0.y + xb4.y, a2 = t0.z + xb4.z, a3 = t0.w + xb4.w;
      float b0 = t1.x + xb4.x, b1 = t1.y + xb4.y, b2 = t1.z + xb4.z, b3 = t1.w + xb4.w;
      u32x2 bpa, bpb;
      bpa[0] = (uint32_t)f2bf(a0 * LOG2E) | ((uint32_t)f2bf(a1 * LOG2E) << 16);
      bpa[1] = (uint32_t)f2bf(a2 * LOG2E) | ((uint32_t)f2bf(a3 * LOG2E) << 16);
      bpb[0] = (uint32_t)f2bf(b0 * LOG2E) | ((uint32_t)f2bf(b1 * LOG2E) << 16);
      bpb[1] = (uint32_t)f2bf(b2 * LOG2E) | ((uint32_t)f2bf(b3 * LOG2E) << 16);
      *(u32x2*)(base2 + off_a) = bpa;
      *(u32x2*)(base2 + off_b) = bpb;
      f32x4 pva = {sigclip(a0), sigclip(a1), sigclip(a2), sigclip(a3)};
      f32x4 pvb = {sigclip(b0), sigclip(b1), sigclip(b2), sigclip(b3)};
      __builtin_nontemporal_store(pva, (f32x4*)(ps_out + off_a));
      __builtin_nontemporal_store(pvb, (f32x4*)(ps_out + off_b));
      // one threefry per paired element: x0=fi (first half), x1=fi+HH (second half)
      uint32_t fi = (uint32_t)off_a;
      uint32_t r0, r1;
      f32x4 xva, xvb;
      tf2x32(kx0, kx1, fi + 0u, fi + 0u + HH, r0, r1);
      xva[0] = ((__uint_as_float(0x3f800000u | (r0 >> 9)) - 1.0f) < pva[0]) ? 1.0f : 0.0f;
      xvb[0] = ((__uint_as_float(0x3f800000u | (r1 >> 9)) - 1.0f) < pvb[0]) ? 1.0f : 0.0f;
      tf2x32(kx0, kx1, fi + 1u, fi + 1u + HH, r0, r1);
      xva[1] = ((__uint_as_float(0x3f800000u | (r0 >> 9)) - 1.0f) < pva[1]) ? 1.0f : 0.0f;
      xvb[1] = ((__uint_as_float(0x3f800000u | (r1 >> 9)) - 1.0f) < pvb[1]) ? 1.0f : 0.0f;
      tf2x32(kx0, kx1, fi + 2u, fi + 2u + HH, r0, r1);
      xva[2] = ((__uint_as_float(0x3f800000u | (r0 >> 9)) - 1.0f) < pva[2]) ? 1.0f : 0.0f;
      xvb[2] = ((__uint_as_float(0x3f800000u | (r1 >> 9)) - 1.0f) < pvb[2]) ? 1.0f : 0.0f;
      tf2x32(kx0, kx1, fi + 3u, fi + 3u + HH, r0, r1);
      xva[3] = ((__uint_as_float(0x3f800000u | (r0 >> 9)) - 1.0f) < pva[3]) ? 1.0f : 0.0f;
      xvb[3] = ((__uint_as_float(0x3f800000u | (r1 >> 9)) - 1.0f) < pvb[3]) ? 1.0f : 0.0f;
      __builtin_nontemporal_store(xva, (f32x4*)(xo_out + off_a));
      __builtin_nontemporal_store(xvb, (f32x4*)(xo_out + off_b));
    }
  }
}

// ---------------- K6: logp_x via MFMA delta-GEMM + fused softplus (log2-space) ----------
// (proven low-VGPR form: 28 VGPR, occupancy ~70%)
__global__ __launch_bounds__(256) void k6_mfma(const ushort* __restrict__ base2,
                                               const ushort* __restrict__ Vkpad2,
                                               const float* __restrict__ xin,
                                               const uint32_t* __restrict__ projb,
                                               const ull* __restrict__ Spack,
                                               const float* __restrict__ Syd,
                                               float* __restrict__ logpx) {
  __shared__ float bvsm[NX];  // b2 per x — 8 KB
  __shared__ float lsum[4][32];
  __shared__ float red[4];
  int sb = blockIdx.x;
  int b = sb & (NB - 1);
  int tid = threadIdx.x;
  int wave = tid >> 6, lane = tid & 63;
  int grp = lane >> 4, col = lane & 15;
  // stage base2 row (bf16 -> f32) + analytic sum_x s*b2
  const uint4* b16p = (const uint4*)(base2 + (size_t)sb * NX);
  const float4* x4p = (const float4*)(xin + (size_t)b * NX);
  float sbacc = 0.0f;
  {
    uint4 bu = b16p[tid];
    float4 xv0 = x4p[tid * 2], xv1 = x4p[tid * 2 + 1];
    uint32_t wds[4] = {bu.x, bu.y, bu.z, bu.w};
    float bv[8];
#pragma unroll
    for (int j = 0; j < 8; ++j) {
      uint32_t wd = wds[j >> 1];
      bv[j] = __uint_as_float((j & 1) ? (wd & 0xFFFF0000u) : (wd << 16));
    }
    float sg[8] = {1.0f - 2.0f * xv0.x, 1.0f - 2.0f * xv0.y, 1.0f - 2.0f * xv0.z,
                   1.0f - 2.0f * xv0.w, 1.0f - 2.0f * xv1.x, 1.0f - 2.0f * xv1.y,
                   1.0f - 2.0f * xv1.z, 1.0f - 2.0f * xv1.w};
#pragma unroll
    for (int j = 0; j < 8; ++j) {
      bvsm[tid * 8 + j] = bv[j];
      sbacc = fmaf(sg[j], bv[j], sbacc);
    }
  }
  float Sb = blockReduceSum256(sbacc, red);  // includes syncthreads (guards bvsm)
  // A-frags: lane holds m=col (t within tile), k = grp*8+j
  uint32_t s25 = (uint32_t)(Spack[sb * 4] & 0x1FFFFFFull);
  uint32_t pb0 = projb[sb * 32 + col];
  uint32_t pb1 = projb[sb * 32 + 16 + col];
  bf16x8 a0, a1;
  union { ushort u; __bf16 hh; } cvt;
#pragma unroll
  for (int j = 0; j < 8; ++j) {
    int k = grp * 8 + j;
    int sbit = (int)((s25 >> k) & 1u);
    int d0 = (int)((pb0 >> k) & 1u) - sbit;
    int d1 = (int)((pb1 >> k) & 1u) - sbit;
    cvt.u = (ushort)(d0 == 0 ? 0 : (d0 > 0 ? 0x3F80 : 0xBF80)); a0[j] = cvt.hh;
    cvt.u = (ushort)(d1 == 0 ? 0 : (d1 > 0 ? 0x3F80 : 0xBF80)); a1[j] = cvt.hh;
  }
  float acca[8], pp[8];
#pragma unroll
  for (int r = 0; r < 8; ++r) { acca[r] = 0.0f; pp[r] = 1.0f; }
  const ushort* vkbase = Vkpad2 + (size_t)(wave * 512 + col) * 32 + grp * 8;
#pragma unroll 4
  for (int i = 0; i < 32; ++i) {
    int x = (wave * 32 + i) * 16 + col;
    bf16x8 bfr = *(const bf16x8*)(vkbase + (size_t)i * 16 * 32);
    f32x4 c0 = {0.f, 0.f, 0.f, 0.f}, c1 = {0.f, 0.f, 0.f, 0.f};
    c0 = __builtin_amdgcn_mfma_f32_16x16x32_bf16(a0, bfr, c0, 0, 0, 0);
    c1 = __builtin_amdgcn_mfma_f32_16x16x32_bf16(a1, bfr, c1, 0, 0, 0);
    float bs = bvsm[x];
#pragma unroll
    for (int r = 0; r < 4; ++r) {
      float y0 = bs + c0[r];
      acca[r] += fabsf(y0);
      pp[r] = fmaf(pp[r], __builtin_amdgcn_exp2f(-fabsf(y0)), pp[r]);
      float y1 = bs + c1[r];
      acca[4 + r] += fabsf(y1);
      pp[4 + r] = fmaf(pp[4 + r], __builtin_amdgcn_exp2f(-fabsf(y1)), pp[4 + r]);
    }
  }
#pragma unroll
  for (int r = 0; r < 8; ++r) {
    float m = 0.5f * acca[r] + __log2f(pp[r]);
#pragma unroll
    for (int off = 1; off < 16; off <<= 1) m += __shfl_xor(m, off);
    if (col == 0) {
      int t = (r < 4) ? (grp * 4 + r) : (16 + grp * 4 + (r - 4));
      lsum[wave][t] = m;
    }
  }
  __syncthreads();
  if (tid < NT) {
    float tot = lsum[0][tid] + lsum[1][tid] + lsum[2][tid] + lsum[3][tid];
    tot += 0.5f * (Sb + Syd[sb * 32 + tid]);
    logpx[(size_t)tid * SBTOT + sb] = -LN2 * tot;
  }
}

// ---------------- K7: per-t weighted reduction, split over 8 b-chunks ----------------
__global__ __launch_bounds__(64) void k7_reduce(const float* __restrict__ logpx,
                                                const uint32_t* __restrict__ projb,
                                                const float* __restrict__ qtail,
                                                const float* __restrict__ ptail,
                                                const float* __restrict__ baseq,
                                                const float* __restrict__ d_lq,
                                                const float* __restrict__ d_lpz,
                                                const float* __restrict__ basepz,
                                                double* __restrict__ pelbo_part) {
  int t = blockIdx.x;
  int chunk = blockIdx.y;
  int lane = threadIdx.x;
  int b = chunk * 64 + lane;
  float dlq[NK];
#pragma unroll
  for (int j = 0; j < NK; ++j) dlq[j] = d_lq[b * NZ + j];
  float bq = baseq[b];
  float bpz = *basepz;
  float lq[NS], lp[NS];
#pragma unroll
  for (int s = 0; s < NS; ++s) {
    int sb = s * NB + b;
    uint32_t m = projb[sb * 32 + t];
    float sq = 0.0f, spv = 0.0f;
#pragma unroll
    for (int j = 0; j < NK; ++j) {
      float on = (float)((m >> j) & 1u);
      sq += on * dlq[j];
      spv += on * d_lpz[j];
    }
    lq[s] = bq + qtail[sb] + sq;
    lp[s] = logpx[t * SBTOT + sb] + bpz + ptail[sb] + spv;
  }
  float mx = lq[0];
#pragma unroll
  for (int s = 1; s < NS; ++s) mx = fmaxf(mx, lq[s]);
  float den = 0.0f, num = 0.0f;
#pragma unroll
  for (int s = 0; s < NS; ++s) {
    float w = __expf(lq[s] - mx);
    den += w;
    num += w * (lq[s] - lp[s]);
  }
  double v = (double)(num / den);
#pragma unroll
  for (int o = 32; o > 0; o >>= 1) v += __shfl_down(v, o);
  if (lane == 0) pelbo_part[t * 8 + chunk] = v;
}

// ---------------- K8: final loss (sum 8 parts per t, mean over t) ----------------
__global__ __launch_bounds__(64) void k8_loss(const double* __restrict__ pelbo_part,
                                              float* __restrict__ out_loss) {
  int t = threadIdx.x;
  double v = 0.0;
  if (t < NT) {
#pragma unroll
    for (int c = 0; c < 8; ++c) v += pelbo_part[t * 8 + c];
  }
#pragma unroll
  for (int o = 32; o > 0; o >>= 1) v += __shfl_down(v, o);
  if (t == 0) *out_loss = (float)(v / (double)NT);
}

extern "C" void kernel_launch(void* const* d_in, const int* in_sizes, int n_in,
                              void* d_out, int out_size, void* d_ws, size_t ws_size,
                              hipStream_t stream) {
  const float* xin = (const float*)d_in[0];
  const float* U = (const float*)d_in[1];
  const float* V = (const float*)d_in[2];
  const float* x_bias = (const float*)d_in[3];
  const float* z_bias = (const float*)d_in[4];
  float* out = (float*)d_out;

  char* p = (char*)d_ws;
  ushort* base2 = (ushort*)p;             p += (size_t)SBTOT * NX * 2;
  float* d_lq = (float*)p;                p += (size_t)NB * NZ * 4;
  float* baseq = (float*)p;               p += (size_t)NB * 4;
  float* d_lpz = (float*)p;               p += (size_t)NZ * 4;
  float* basepz = (float*)p;              p += 16;
  ull* Spack = (ull*)p;                   p += (size_t)SBTOT * 4 * 8;
  float* qtail = (float*)p;               p += (size_t)SBTOT * 4;
  float* ptail = (float*)p;               p += (size_t)SBTOT * 4;
  ull* Ct = (ull*)p;                      p += (size_t)NT * NK * 4 * 8;
  uint32_t* bpm = (uint32_t*)p;           p += 128;
  uint32_t* projb = (uint32_t*)p;         p += (size_t)SBTOT * 32 * 4;
  float* Syd = (float*)p;                 p += (size_t)SBTOT * 32 * 4;
  float* logpx = (float*)p;               p += (size_t)NT * SBTOT * 4;
  double* pelbo = (double*)p;             p += (size_t)NT * 8 * 8;
  ushort* Vkpad2 = (ushort*)p;            p += (size_t)NX * 32 * 2;
  ushort* Vbf = (ushort*)p;               p += (size_t)NX * NZ * 2;
  ushort* samp16 = (ushort*)p;            p += (size_t)SBTOT * NZ * 2;
  float* W = (float*)p;                   p += (size_t)NB * 32 * 4;
  ushort* Uhi = (ushort*)p;               p += (size_t)NZ * NX * 2;
  ushort* Ulo = (ushort*)p;               p += (size_t)NZ * NX * 2;
  ushort* xinbf = (ushort*)p;             p += (size_t)NB * NX * 2;
  (void)ws_size; (void)in_sizes; (void)n_in; (void)out_size;

  // JAX: key(42) -> split 4 -> kz,kx,kA,kb
  uint32_t o0[4], o1[4];
  for (int j = 0; j < 4; ++j) tf2x32(0u, 42u, (uint32_t)j, (uint32_t)(4 + j), o0[j], o1[j]);
  uint32_t kz0 = o0[0], kz1 = o0[1];
  uint32_t kx0 = o0[2], kx1 = o0[3];
  uint32_t kA0 = o1[0], kA1 = o1[1];
  uint32_t kb0 = o1[2], kb1 = o1[3];

  kP0_prep<<<NX * NZ / 256 + NT, 256, 0, stream>>>(V, U, xin, z_bias, Vbf, Vkpad2,
                                                   Uhi, Ulo, xinbf, baseq, d_lpz, basepz,
                                                   Ct, bpm, kA0, kA1, kb0, kb1);
  k1w_mfma<<<1024, 256, 0, stream>>>(xinbf, Uhi, Ulo, z_bias, xin, Vkpad2,
                                     out + OFF_Q, d_lq, baseq, W);
  k2_samples<<<SBTOT, 256, 0, stream>>>(out + OFF_Q, d_lq, d_lpz, Ct, bpm, W,
                                        out + OFF_SAMP, samp16, Spack, qtail, ptail,
                                        projb, Syd, kz0, kz1);
  dim3 g3(NX / 128, SBTOT / 64);
  k3m_gemm<<<g3, 256, 0, stream>>>(samp16, Vbf, x_bias, base2,
                                   out + OFF_PS, out + OFF_XO, kx0, kx1);
  k6_mfma<<<SBTOT, 256, 0, stream>>>(base2, Vkpad2, xin, projb, Spack, Syd, logpx);
  dim3 g7(NT, 8);
  k7_reduce<<<g7, 64, 0, stream>>>(logpx, projb, qtail, ptail, baseq, d_lq,
                                   d_lpz, basepz, pelbo);
  k8_loss<<<1, 64, 0, stream>>>(pelbo, out + OFF_LOSS);
}

// Round 6
// 254.618 us; speedup vs baseline: 1.0602x; 1.0082x over previous
//
#include <hip/hip_runtime.h>
#include <cstdint>

// Problem constants (setup_inputs fixed: nx=2048, nz=256, B=512, S=10, k=25, T=30)
#define NX 2048
#define NZ 256
#define NB 512
#define NS 10
#define NK 25
#define NT 30
#define SBTOT (NS * NB)  // 5120

#define LOG2E 1.4426950408889634f
#define LN2 0.6931471805599453f

// d_out flat layout (all float32): q, samples_z, ps, xouts, loss
#define OFF_Q 0
#define OFF_SAMP (NB * NZ)
#define OFF_PS (OFF_SAMP + SBTOT * NZ)
#define OFF_XO (OFF_PS + SBTOT * NX)
#define OFF_LOSS (OFF_XO + SBTOT * NX)

typedef unsigned long long ull;
typedef __bf16 bf16x8 __attribute__((ext_vector_type(8)));
typedef float f32x4 __attribute__((ext_vector_type(4)));
typedef uint32_t u32x2 __attribute__((ext_vector_type(2)));

// ---------------- JAX Threefry-2x32 (exact) ----------------
__host__ __device__ inline void tf2x32(uint32_t k0, uint32_t k1, uint32_t x0, uint32_t x1,
                                       uint32_t& o0, uint32_t& o1) {
  uint32_t k2 = k0 ^ k1 ^ 0x1BD11BDAu;
  x0 += k0; x1 += k1;
#define TF_R(r) { x0 += x1; x1 = (x1 << (r)) | (x1 >> (32 - (r))); x1 ^= x0; }
  TF_R(13) TF_R(15) TF_R(26) TF_R(6)
  x0 += k1; x1 += k2 + 1u;
  TF_R(17) TF_R(29) TF_R(16) TF_R(24)
  x0 += k2; x1 += k0 + 2u;
  TF_R(13) TF_R(15) TF_R(26) TF_R(6)
  x0 += k0; x1 += k1 + 3u;
  TF_R(17) TF_R(29) TF_R(16) TF_R(24)
  x0 += k1; x1 += k2 + 4u;
  TF_R(13) TF_R(15) TF_R(26) TF_R(6)
  x0 += k2; x1 += k0 + 5u;
#undef TF_R
  o0 = x0; o1 = x1;
}

// JAX threefry over iota(n): element i (h=n/2): i<h -> o0(i,i+h); else o1(i-h,i)
__device__ inline uint32_t tf_select(uint32_t k0, uint32_t k1, uint32_t i, uint32_t h) {
  bool lo = i < h;
  uint32_t x0 = lo ? i : i - h;
  uint32_t x1 = lo ? i + h : i;
  uint32_t o0, o1;
  tf2x32(k0, k1, x0, x1, o0, o1);
  return lo ? o0 : o1;
}

__device__ inline float tf_uniform(uint32_t k0, uint32_t k1, uint32_t i, uint32_t h) {
  uint32_t r = tf_select(k0, k1, i, h);
  return __uint_as_float(0x3f800000u | (r >> 9)) - 1.0f;  // [0,1), exactly JAX
}

__device__ inline float sigclip(float a) {
  float p = 1.0f / (1.0f + __expf(-a));
  return fminf(fmaxf(p, 1e-6f), 1.0f - 1e-6f);
}

__device__ inline ushort f2bf(float f) {  // RNE f32->bf16 (no NaN inputs here)
  uint32_t u = __float_as_uint(f);
  return (ushort)((u + 0x7FFFu + ((u >> 16) & 1u)) >> 16);
}

__device__ inline float blockReduceSum256(float v, volatile float* s4) {
#pragma unroll
  for (int o = 32; o > 0; o >>= 1) v += __shfl_down(v, o);
  __syncthreads();
  if ((threadIdx.x & 63) == 0) s4[threadIdx.x >> 6] = v;
  __syncthreads();
  return s4[0] + s4[1] + s4[2] + s4[3];
}

// ---------------- KP0: prep tables (2048 uniform blocks, no slow tail) ----------
__global__ __launch_bounds__(256) void kP0_prep(const float* __restrict__ V,
                                                const float* __restrict__ U,
                                                const float* __restrict__ xin,
                                                const float* __restrict__ z_bias,
                                                ushort* __restrict__ Vbf,
                                                ushort* __restrict__ Vkpad2,
                                                ushort* __restrict__ Uhi,
                                                ushort* __restrict__ Ulo,
                                                ushort* __restrict__ xinbf,
                                                float* __restrict__ baseq,
                                                float* __restrict__ d_lpz,
                                                float* __restrict__ basepz,
                                                double* __restrict__ loss_acc,
                                                uint32_t* __restrict__ done_ctr) {
  __shared__ float red[4];
  int tid = threadIdx.x;
  int e = blockIdx.x * 256 + tid;  // < NX*NZ = 524288
  {  // V
    int x = e >> 8, k = e & 255;
    float v = V[e];
    Vbf[e] = f2bf(v);
    if (k < 32) Vkpad2[x * 32 + k] = (k < NK) ? f2bf(v * LOG2E) : (ushort)0;
  }
  {  // U split hi/lo (U is [NZ][NX], 524288 elements)
    float u = U[e];
    ushort hi = f2bf(u);
    Uhi[e] = hi;
    float hv = __uint_as_float((uint32_t)hi << 16);
    Ulo[e] = f2bf(u - hv);
  }
  {  // xin cast (1048576 elements, 2 per thread)
    xinbf[e] = (xin[e] > 0.5f) ? (ushort)0x3F80 : (ushort)0;
    int e2 = e + NX * NZ;
    xinbf[e2] = (xin[e2] > 0.5f) ? (ushort)0x3F80 : (ushort)0;
  }
  if (e < NB) baseq[e] = 0.0f;
  if (blockIdx.x == 0) {
    if (tid == 0) { *loss_acc = 0.0; *done_ctr = 0u; }
    int z = tid;
    float pz = sigclip(z_bias[z]);
    float lp = __logf(pz), l1 = __logf(1.0f - pz);
    d_lpz[z] = lp - l1;
    float s = blockReduceSum256(l1, red);
    if (z == 0) *basepz = s;
  }
}

// ---------------- K1W: q-GEMM (blocks 0..511) + W signdot (512..1023) + k4 GF(2) (1024..1053)
__global__ __launch_bounds__(256) void k1w_mfma(const ushort* __restrict__ xinbf,
                                                const ushort* __restrict__ Uhi,
                                                const ushort* __restrict__ Ulo,
                                                const float* __restrict__ z_bias,
                                                const float* __restrict__ xin,
                                                const ushort* __restrict__ Vkpad2,
                                                float* __restrict__ outq,
                                                float* __restrict__ d_lq,
                                                float* __restrict__ baseq,
                                                float* __restrict__ W,
                                                ull* __restrict__ Ct,
                                                uint32_t* __restrict__ bpmask,
                                                uint32_t kA0, uint32_t kA1,
                                                uint32_t kb0, uint32_t kb1) {
  __shared__ float red[4][16][17];
  __shared__ float wred[4][NK];
  __shared__ uint32_t Aw[NK][8];
  __shared__ uint32_t bbsh[NK];
  int tid = threadIdx.x;
  if (blockIdx.x >= 1024) {
    // ---- k4 body: GF(2) row reduce for t = blockIdx.x - 1024 ----
    // (independent of kP0/k1w outputs: pure RNG; overlaps with GEMM blocks;
    //  only k2 consumes Ct/bpmask)
    int t = blockIdx.x - 1024;
    if (tid < NK * 8) {
      int r = tid >> 3, c = tid & 7;
      const uint32_t hA = (uint32_t)NT * NK * NZ / 2;
      uint32_t base_i = (uint32_t)(t * NK + r) * NZ + c * 32;
      uint32_t w = 0;
      for (int zz = 0; zz < 32; ++zz) {
        uint32_t rr = tf_select(kA0, kA1, base_i + zz, hA);
        w |= ((rr >> 31) ^ 1u) << zz;  // bit=1 iff u<0.5 (top bit 0)
      }
      Aw[r][c] = w;
    }
    if (tid < NK) {
      const uint32_t hb = (uint32_t)NT * NK / 2;
      uint32_t rb = tf_select(kb0, kb1, (uint32_t)(t * NK + tid), hb);
      bbsh[tid] = (rb >> 31) ^ 1u;
    }
    __syncthreads();
    if (tid >= 64) return;  // wave 0 does the elimination
    int lane = tid;
    ull w0 = 0, w1 = 0, w2 = 0, w3 = 0;
    uint32_t bbit = 0;
    if (lane < NK) {
      w0 = (ull)Aw[lane][0] | ((ull)Aw[lane][1] << 32);
      w1 = (ull)Aw[lane][2] | ((ull)Aw[lane][3] << 32);
      w2 = (ull)Aw[lane][4] | ((ull)Aw[lane][5] << 32);
      w3 = (ull)Aw[lane][6] | ((ull)Aw[lane][7] << 32);
      bbit = bbsh[lane];
    }
    for (int i = 0; i < NK; ++i) {
      int mybit = (int)((w0 >> i) & 1ull);
      ull mask = __ballot(lane < NK && mybit);
      ull cand = mask & (~0ull << i);
      int p = cand ? __builtin_ctzll(cand) : (NK - 1);
      int srcl = (lane == i) ? p : ((lane == p) ? i : lane);
      w0 = __shfl(w0, srcl); w1 = __shfl(w1, srcl); w2 = __shfl(w2, srcl); w3 = __shfl(w3, srcl);
      bbit = __shfl(bbit, srcl);
      ull p0 = __shfl(w0, i), p1 = __shfl(w1, i), p2 = __shfl(w2, i), p3 = __shfl(w3, i);
      uint32_t pvb = __shfl(bbit, i);
      int nb2 = (int)((w0 >> i) & 1ull);
      if (lane < NK && lane != i && nb2) {
        w0 ^= p0; w1 ^= p1; w2 ^= p2; w3 ^= p3; bbit ^= pvb;
      }
    }
    if (lane < NK) {
      w0 &= ~((1ull << NK) - 1ull);  // only columns z>=k feed proj
      ull* dstp = Ct + (size_t)(t * NK + lane) * 4;
      dstp[0] = w0; dstp[1] = w1; dstp[2] = w2; dstp[3] = w3;
    }
    ull bm = __ballot(lane < NK && bbit);
    if (lane == 0) bpmask[t] = (uint32_t)bm & 0x1FFFFFFu;
    return;
  }
  if (blockIdx.x < 512) {
    // ---- k1a body: q-GEMM via MFMA hi/lo split-K (exact to ~fp32) ----
    int wave = tid >> 6, lane = tid & 63, grp = lane >> 4, col = lane & 15;
    int b0 = (blockIdx.x >> 4) * 16;
    int z0 = (blockIdx.x & 15) * 16;
    f32x4 acc = {0.f, 0.f, 0.f, 0.f};
    const ushort* arow = xinbf + (size_t)(b0 + col) * NX + wave * 512 + grp * 8;
    const ushort* bhr = Uhi + (size_t)(z0 + col) * NX + wave * 512 + grp * 8;
    const ushort* blr = Ulo + (size_t)(z0 + col) * NX + wave * 512 + grp * 8;
#pragma unroll 4
    for (int s = 0; s < 16; ++s) {
      bf16x8 a = *(const bf16x8*)(arow + s * 32);
      bf16x8 bh = *(const bf16x8*)(bhr + s * 32);
      bf16x8 bl = *(const bf16x8*)(blr + s * 32);
      acc = __builtin_amdgcn_mfma_f32_16x16x32_bf16(a, bh, acc, 0, 0, 0);
      acc = __builtin_amdgcn_mfma_f32_16x16x32_bf16(a, bl, acc, 0, 0, 0);
    }
#pragma unroll
    for (int r = 0; r < 4; ++r) red[wave][grp * 4 + r][col] = acc[r];
    __syncthreads();
    int bi = tid >> 4, zi = tid & 15;
    float aa = red[0][bi][zi] + red[1][bi][zi] + red[2][bi][zi] + red[3][bi][zi] + z_bias[z0 + zi];
    int b = b0 + bi, z = z0 + zi;
    float q = sigclip(aa);
    outq[b * NZ + z] = q;
    float lq = __logf(q), l1 = __logf(1.0f - q);
    d_lq[b * NZ + z] = lq - l1;
    float s1 = l1;
#pragma unroll
    for (int o = 1; o < 16; o <<= 1) s1 += __shfl_xor(s1, o);
    if (zi == 0) atomicAdd(&baseq[b], s1);
    return;
  }
  // ---- kW body: W[b][k] = sum_x (1-2*xin[b,x]) * bf16val(Vkpad2[x,k]) ----
  int b = blockIdx.x - 512;
  float acc[NK];
#pragma unroll
  for (int j = 0; j < NK; ++j) acc[j] = 0.0f;
#pragma unroll
  for (int i = 0; i < 8; ++i) {
    int x = i * 256 + tid;
    float s = 1.0f - 2.0f * xin[(size_t)b * NX + x];
    const uint4* vp = (const uint4*)(Vkpad2 + (size_t)x * 32);
    uint4 q0 = vp[0], q1 = vp[1], q2 = vp[2], q3 = vp[3];
    uint32_t w[16] = {q0.x, q0.y, q0.z, q0.w, q1.x, q1.y, q1.z, q1.w,
                      q2.x, q2.y, q2.z, q2.w, q3.x, q3.y, q3.z, q3.w};
#pragma unroll
    for (int j = 0; j < NK; ++j) {
      uint32_t wd = w[j >> 1];
      float v = __uint_as_float((j & 1) ? (wd & 0xFFFF0000u) : (wd << 16));
      acc[j] = fmaf(s, v, acc[j]);
    }
  }
#pragma unroll
  for (int j = 0; j < NK; ++j) {
#pragma unroll
    for (int o = 1; o < 64; o <<= 1) acc[j] += __shfl_xor(acc[j], o);
  }
  if ((tid & 63) == 0) {
#pragma unroll
    for (int j = 0; j < NK; ++j) wred[tid >> 6][j] = acc[j];
  }
  __syncthreads();
  if (tid < NK) W[b * 32 + tid] = wred[0][tid] + wred[1][tid] + wred[2][tid] + wred[3][tid];
}

// ---------------- K2: samples + packed bits + tails + FUSED proj/Syd -----
__global__ __launch_bounds__(256) void k2_samples(const float* __restrict__ q,
                                                  const float* __restrict__ d_lq,
                                                  const float* __restrict__ d_lpz,
                                                  const ull* __restrict__ Ct,
                                                  const uint32_t* __restrict__ bpmask,
                                                  const float* __restrict__ W,
                                                  float* __restrict__ samp_out,
                                                  ushort* __restrict__ samp16,
                                                  ull* __restrict__ Spack,
                                                  float* __restrict__ qtail,
                                                  float* __restrict__ ptail,
                                                  uint32_t* __restrict__ projb,
                                                  float* __restrict__ Syd,
                                                  uint32_t kz0, uint32_t kz1) {
  __shared__ float red[4];
  __shared__ ull sp_sh[4];
  int sb = blockIdx.x;
  int z = threadIdx.x;
  int b = sb & (NB - 1);
  uint32_t i = (uint32_t)sb * NZ + z;
  const uint32_t h = (uint32_t)SBTOT * NZ / 2;
  float u = tf_uniform(kz0, kz1, i, h);
  float qv = q[b * NZ + z];
  int smp = (u < qv) ? 1 : 0;
  __builtin_nontemporal_store((float)smp, samp_out + i);  // pure output: stream
  samp16[i] = smp ? (ushort)0x3F80 : (ushort)0;
  ull m = __ballot(smp);
  if ((z & 63) == 0) { Spack[sb * 4 + (z >> 6)] = m; sp_sh[z >> 6] = m; }
  float dq = (z >= NK && smp) ? d_lq[b * NZ + z] : 0.0f;
  float dp = (z >= NK && smp) ? d_lpz[z] : 0.0f;
  float sq = blockReduceSum256(dq, red);  // syncthreads inside publish sp_sh
  float sp = blockReduceSum256(dp, red);
  if (z == 0) { qtail[sb] = sq; ptail[sb] = sp; }
  // ---- fused k5: threads 0..31 compute projb/Syd for this sb ----
  if (z < 32) {
    int t = z;
    ull s0 = sp_sh[0], s1 = sp_sh[1], s2 = sp_sh[2], s3 = sp_sh[3];
    uint32_t s25 = (uint32_t)(s0 & 0x1FFFFFFull);
    const float* Wb = W + (size_t)b * 32;
    uint32_t out;
    float syd = 0.0f;
    if (t < NT) {
      uint32_t bp = bpmask[t];
      uint32_t pb = 0;
#pragma unroll
      for (int j = 0; j < NK; ++j) {
        const ull* C = Ct + (size_t)(t * NK + j) * 4;
        int par = __popcll(s0 & C[0]) + __popcll(s1 & C[1]) + __popcll(s2 & C[2]) + __popcll(s3 & C[3]);
        uint32_t bit = ((uint32_t)(par ^ (int)(bp >> j))) & 1u;
        pb |= bit << j;
        int d = (int)bit - (int)((s25 >> j) & 1u);
        syd = fmaf((float)d, Wb[j], syd);
      }
      out = pb;
    } else {
      out = s25;  // d = pb - s25 = 0
    }
    projb[sb * 32 + t] = out;
    Syd[sb * 32 + t] = syd;
  }
}

// ---------------- K3M: bf16 MFMA GEMM (operand-swapped): C[x][sb] = V·samp^T ------
__global__ __launch_bounds__(256) void k3m_gemm(const ushort* __restrict__ samp16,
                                                const ushort* __restrict__ Vbf,
                                                const float* __restrict__ x_bias,
                                                ushort* __restrict__ base2,
                                                float* __restrict__ ps_out,
                                                float* __restrict__ xo_out,
                                                uint32_t kx0, uint32_t kx1) {
  // Aliased LDS: GEMM staging As(8KB)+Bs(4KB); epilogue 2 tiles [16][132] f32.
  __shared__ __align__(16) char smem[2 * 2112 * 4];  // 16896 B
  ushort* As = (ushort*)smem;          // V rows (x)     128*32 bf16
  ushort* Bs = (ushort*)(smem + 8192); // samp rows (sb)  64*32 bf16
  float* Tt = (float*)smem;            // epilogue tiles

  int tid = threadIdx.x;
  int wave = tid >> 6, lane = tid & 63, grp = lane >> 4, col = lane & 15;
  int x0 = blockIdx.x * 128;
  int sb0 = blockIdx.y * 32;  // first-half base; pair rows at sb0 + SBTOT/2
  f32x4 acc[2][4];
#pragma unroll
  for (int mi = 0; mi < 2; ++mi)
#pragma unroll
    for (int ni = 0; ni < 4; ++ni) acc[mi][ni] = (f32x4){0.f, 0.f, 0.f, 0.f};

  for (int k0 = 0; k0 < NZ; k0 += 32) {
    {
      int rowb = tid >> 2, kcb = (tid & 3) << 3;
      int sbrow = (rowb < 32) ? (sb0 + rowb) : (sb0 + 2528 + rowb);  // 2560+(rowb-32)
      *(uint4*)&Bs[rowb * 32 + kcb] = *(const uint4*)&samp16[(size_t)sbrow * NZ + k0 + kcb];
#pragma unroll
      for (int c = tid; c < 512; c += 256) {
        int rowa = c >> 2, kca = (c & 3) << 3;
        *(uint4*)&As[rowa * 32 + kca] = *(const uint4*)&Vbf[(size_t)(x0 + rowa) * NZ + k0 + kca];
      }
    }
    __syncthreads();
    bf16x8 af[2], bfv[4];
#pragma unroll
    for (int mi = 0; mi < 2; ++mi)
      af[mi] = *(const bf16x8*)&As[(wave * 32 + mi * 16 + col) * 32 + grp * 8];
#pragma unroll
    for (int ni = 0; ni < 4; ++ni)
      bfv[ni] = *(const bf16x8*)&Bs[(ni * 16 + col) * 32 + grp * 8];
#pragma unroll
    for (int mi = 0; mi < 2; ++mi)
#pragma unroll
      for (int ni = 0; ni < 4; ++ni)
        acc[mi][ni] = __builtin_amdgcn_mfma_f32_16x16x32_bf16(af[mi], bfv[ni], acc[mi][ni], 0, 0, 0);
    __syncthreads();
  }

  // ---- epilogue: LDS transpose for coalesced stores + paired threefry ----
  const uint32_t HH = (uint32_t)(SBTOT / 2) * (uint32_t)NX;  // 5242880
#pragma unroll
  for (int pi = 0; pi < 2; ++pi) {
    __syncthreads();  // previous reads of smem complete
#pragma unroll
    for (int mi = 0; mi < 2; ++mi) {
      int cbase = wave * 32 + mi * 16 + grp * 4;
      *(float4*)&Tt[col * 132 + cbase] = *(float4*)&acc[mi][pi];          // sb_a tile
      *(float4*)&Tt[2112 + col * 132 + cbase] = *(float4*)&acc[mi][pi + 2];  // sb_b tile
    }
    __syncthreads();
#pragma unroll
    for (int pass = 0; pass < 2; ++pass) {
      int r = pass * 8 + (tid >> 5);   // sb-local row 0..15
      int c = (tid & 31) * 4;          // x-local col, float4 granularity
      float4 t0 = *(float4*)&Tt[r * 132 + c];
      float4 t1 = *(float4*)&Tt[2112 + r * 132 + c];
      float4 xb4 = *(const float4*)(x_bias + x0 + c);
      int sb_a = sb0 + pi * 16 + r;                 // < SBTOT/2
      size_t off_a = (size_t)sb_a * NX + x0 + c;
      size_t off_b = off_a + (size_t)HH;
      float a0 = t0.x + xb4.x, a1 = t0.y + xb4.y, a2 = t0.z + xb4.z, a3 = t0.w + xb4.w;
      float b0 = t1.x + xb4.x, b1 = t1.y + xb4.y, b2 = t1.z + xb4.z, b3 = t1.w + xb4.w;
      u32x2 bpa, bpb;
      bpa[0] = (uint32_t)f2bf(a0 * LOG2E) | ((uint32_t)f2bf(a1 * LOG2E) << 16);
      bpa[1] = (uint32_t)f2bf(a2 * LOG2E) | ((uint32_t)f2bf(a3 * LOG2E) << 16);
      bpb[0] = (uint32_t)f2bf(b0 * LOG2E) | ((uint32_t)f2bf(b1 * LOG2E) << 16);
      bpb[1] = (uint32_t)f2bf(b2 * LOG2E) | ((uint32_t)f2bf(b3 * LOG2E) << 16);
      *(u32x2*)(base2 + off_a) = bpa;
      *(u32x2*)(base2 + off_b) = bpb;
      f32x4 pva = {sigclip(a0), sigclip(a1), sigclip(a2), sigclip(a3)};
      f32x4 pvb = {sigclip(b0), sigclip(b1), sigclip(b2), sigclip(b3)};
      __builtin_nontemporal_store(pva, (f32x4*)(ps_out + off_a));
      __builtin_nontemporal_store(pvb, (f32x4*)(ps_out + off_b));
      // one threefry per paired element: x0=fi (first half), x1=fi+HH (second half)
      uint32_t fi = (uint32_t)off_a;
      uint32_t r0, r1;
      f32x4 xva, xvb;
      tf2x32(kx0, kx1, fi + 0u, fi + 0u + HH, r0, r1);
      xva[0] = ((__uint_as_float(0x3f800000u | (r0 >> 9)) - 1.0f) < pva[0]) ? 1.0f : 0.0f;
      xvb[0] = ((__uint_as_float(0x3f800000u | (r1 >> 9)) - 1.0f) < pvb[0]) ? 1.0f : 0.0f;
      tf2x32(kx0, kx1, fi + 1u, fi + 1u + HH, r0, r1);
      xva[1] = ((__uint_as_float(0x3f800000u | (r0 >> 9)) - 1.0f) < pva[1]) ? 1.0f : 0.0f;
      xvb[1] = ((__uint_as_float(0x3f800000u | (r1 >> 9)) - 1.0f) < pvb[1]) ? 1.0f : 0.0f;
      tf2x32(kx0, kx1, fi + 2u, fi + 2u + HH, r0, r1);
      xva[2] = ((__uint_as_float(0x3f800000u | (r0 >> 9)) - 1.0f) < pva[2]) ? 1.0f : 0.0f;
      xvb[2] = ((__uint_as_float(0x3f800000u | (r1 >> 9)) - 1.0f) < pvb[2]) ? 1.0f : 0.0f;
      tf2x32(kx0, kx1, fi + 3u, fi + 3u + HH, r0, r1);
      xva[3] = ((__uint_as_float(0x3f800000u | (r0 >> 9)) - 1.0f) < pva[3]) ? 1.0f : 0.0f;
      xvb[3] = ((__uint_as_float(0x3f800000u | (r1 >> 9)) - 1.0f) < pvb[3]) ? 1.0f : 0.0f;
      __builtin_nontemporal_store(xva, (f32x4*)(xo_out + off_a));
      __builtin_nontemporal_store(xvb, (f32x4*)(xo_out + off_b));
    }
  }
}

// ---------------- K6: logp_x via MFMA delta-GEMM + fused softplus (log2-space) ----------
// (low-VGPR form; bias bs folded into MFMA C-operand: saves 8 v_add/iter)
__global__ __launch_bounds__(256) void k6_mfma(const ushort* __restrict__ base2,
                                               const ushort* __restrict__ Vkpad2,
                                               const float* __restrict__ xin,
                                               const uint32_t* __restrict__ projb,
                                               const ull* __restrict__ Spack,
                                               const float* __restrict__ Syd,
                                               float* __restrict__ logpx) {
  __shared__ float bvsm[NX];  // b2 per x — 8 KB
  __shared__ float lsum[4][32];
  __shared__ float red[4];
  int sb = blockIdx.x;
  int b = sb & (NB - 1);
  int tid = threadIdx.x;
  int wave = tid >> 6, lane = tid & 63;
  int grp = lane >> 4, col = lane & 15;
  // stage base2 row (bf16 -> f32) + analytic sum_x s*b2
  const uint4* b16p = (const uint4*)(base2 + (size_t)sb * NX);
  const float4* x4p = (const float4*)(xin + (size_t)b * NX);
  float sbacc = 0.0f;
  {
    uint4 bu = b16p[tid];
    float4 xv0 = x4p[tid * 2], xv1 = x4p[tid * 2 + 1];
    uint32_t wds[4] = {bu.x, bu.y, bu.z, bu.w};
    float bv[8];
#pragma unroll
    for (int j = 0; j < 8; ++j) {
      uint32_t wd = wds[j >> 1];
      bv[j] = __uint_as_float((j & 1) ? (wd & 0xFFFF0000u) : (wd << 16));
    }
    float sg[8] = {1.0f - 2.0f * xv0.x, 1.0f - 2.0f * xv0.y, 1.0f - 2.0f * xv0.z,
                   1.0f - 2.0f * xv0.w, 1.0f - 2.0f * xv1.x, 1.0f - 2.0f * xv1.y,
                   1.0f - 2.0f * xv1.z, 1.0f - 2.0f * xv1.w};
#pragma unroll
    for (int j = 0; j < 8; ++j) {
      bvsm[tid * 8 + j] = bv[j];
      sbacc = fmaf(sg[j], bv[j], sbacc);
    }
  }
  float Sb = blockReduceSum256(sbacc, red);  // includes syncthreads (guards bvsm)
  // A-frags: lane holds m=col (t within tile), k = grp*8+j
  uint32_t s25 = (uint32_t)(Spack[sb * 4] & 0x1FFFFFFull);
  uint32_t pb0 = projb[sb * 32 + col];
  uint32_t pb1 = projb[sb * 32 + 16 + col];
  bf16x8 a0, a1;
  union { ushort u; __bf16 hh; } cvt;
#pragma unroll
  for (int j = 0; j < 8; ++j) {
    int k = grp * 8 + j;
    int sbit = (int)((s25 >> k) & 1u);
    int d0 = (int)((pb0 >> k) & 1u) - sbit;
    int d1 = (int)((pb1 >> k) & 1u) - sbit;
    cvt.u = (ushort)(d0 == 0 ? 0 : (d0 > 0 ? 0x3F80 : 0xBF80)); a0[j] = cvt.hh;
    cvt.u = (ushort)(d1 == 0 ? 0 : (d1 > 0 ? 0x3F80 : 0xBF80)); a1[j] = cvt.hh;
  }
  float acca[8], pp[8];
#pragma unroll
  for (int r = 0; r < 8; ++r) { acca[r] = 0.0f; pp[r] = 1.0f; }
  const ushort* vkbase = Vkpad2 + (size_t)(wave * 512 + col) * 32 + grp * 8;
  const float* bvp = bvsm + wave * 512 + col;
#pragma unroll 4
  for (int i = 0; i < 32; ++i) {
    float bs = bvp[i * 16];
    bf16x8 bfr = *(const bf16x8*)(vkbase + (size_t)i * 16 * 32);
    f32x4 cb = {bs, bs, bs, bs};
    f32x4 c0 = __builtin_amdgcn_mfma_f32_16x16x32_bf16(a0, bfr, cb, 0, 0, 0);
    f32x4 c1 = __builtin_amdgcn_mfma_f32_16x16x32_bf16(a1, bfr, cb, 0, 0, 0);
#pragma unroll
    for (int r = 0; r < 4; ++r) {
      float y0 = c0[r];
      acca[r] += fabsf(y0);
      pp[r] = fmaf(pp[r], __builtin_amdgcn_exp2f(-fabsf(y0)), pp[r]);
      float y1 = c1[r];
      acca[4 + r] += fabsf(y1);
      pp[4 + r] = fmaf(pp[4 + r], __builtin_amdgcn_exp2f(-fabsf(y1)), pp[4 + r]);
    }
  }
#pragma unroll
  for (int r = 0; r < 8; ++r) {
    float m = 0.5f * acca[r] + __log2f(pp[r]);
#pragma unroll
    for (int off = 1; off < 16; off <<= 1) m += __shfl_xor(m, off);
    if (col == 0) {
      int t = (r < 4) ? (grp * 4 + r) : (16 + grp * 4 + (r - 4));
      lsum[wave][t] = m;
    }
  }
  __syncthreads();
  if (tid < NT) {
    float tot = lsum[0][tid] + lsum[1][tid] + lsum[2][tid] + lsum[3][tid];
    tot += 0.5f * (Sb + Syd[sb * 32 + tid]);
    logpx[(size_t)tid * SBTOT + sb] = -LN2 * tot;
  }
}

// ---------------- K7: per-t weighted reduction + FUSED final loss (atomic finalize) ----
__global__ __launch_bounds__(64) void k7_reduce(const float* __restrict__ logpx,
                                                const uint32_t* __restrict__ projb,
                                                const float* __restrict__ qtail,
                                                const float* __restrict__ ptail,
                                                const float* __restrict__ baseq,
                                                const float* __restrict__ d_lq,
                                                const float* __restrict__ d_lpz,
                                                const float* __restrict__ basepz,
                                                double* __restrict__ loss_acc,
                                                uint32_t* __restrict__ done_ctr,
                                                float* __restrict__ out_loss) {
  int t = blockIdx.x;
  int chunk = blockIdx.y;
  int lane = threadIdx.x;
  int b = chunk * 64 + lane;
  float dlq[NK];
#pragma unroll
  for (int j = 0; j < NK; ++j) dlq[j] = d_lq[b * NZ + j];
  float bq = baseq[b];
  float bpz = *basepz;
  float lq[NS], lp[NS];
#pragma unroll
  for (int s = 0; s < NS; ++s) {
    int sb = s * NB + b;
    uint32_t m = projb[sb * 32 + t];
    float sq = 0.0f, spv = 0.0f;
#pragma unroll
    for (int j = 0; j < NK; ++j) {
      float on = (float)((m >> j) & 1u);
      sq += on * dlq[j];
      spv += on * d_lpz[j];
    }
    lq[s] = bq + qtail[sb] + sq;
    lp[s] = logpx[t * SBTOT + sb] + bpz + ptail[sb] + spv;
  }
  float mx = lq[0];
#pragma unroll
  for (int s = 1; s < NS; ++s) mx = fmaxf(mx, lq[s]);
  float den = 0.0f, num = 0.0f;
#pragma unroll
  for (int s = 0; s < NS; ++s) {
    float w = __expf(lq[s] - mx);
    den += w;
    num += w * (lq[s] - lp[s]);
  }
  double v = (double)(num / den);
#pragma unroll
  for (int o = 32; o > 0; o >>= 1) v += __shfl_down(v, o);
  if (lane == 0) {
    atomicAdd(loss_acc, v);
    __threadfence();
    uint32_t old = atomicAdd(done_ctr, 1u);
    if (old == (uint32_t)(NT * 8 - 1)) {
      double tot = atomicAdd(loss_acc, 0.0);  // coherent read of final sum
      *out_loss = (float)(tot / (double)NT);
    }
  }
}

extern "C" void kernel_launch(void* const* d_in, const int* in_sizes, int n_in,
                              void* d_out, int out_size, void* d_ws, size_t ws_size,
                              hipStream_t stream) {
  const float* xin = (const float*)d_in[0];
  const float* U = (const float*)d_in[1];
  const float* V = (const float*)d_in[2];
  const float* x_bias = (const float*)d_in[3];
  const float* z_bias = (const float*)d_in[4];
  float* out = (float*)d_out;

  char* p = (char*)d_ws;
  ushort* base2 = (ushort*)p;             p += (size_t)SBTOT * NX * 2;
  float* d_lq = (float*)p;                p += (size_t)NB * NZ * 4;
  float* baseq = (float*)p;               p += (size_t)NB * 4;
  float* d_lpz = (float*)p;               p += (size_t)NZ * 4;
  float* basepz = (float*)p;              p += 16;
  ull* Spack = (ull*)p;                   p += (size_t)SBTOT * 4 * 8;
  float* qtail = (float*)p;               p += (size_t)SBTOT * 4;
  float* ptail = (float*)p;               p += (size_t)SBTOT * 4;
  ull* Ct = (ull*)p;                      p += (size_t)NT * NK * 4 * 8;
  uint32_t* bpm = (uint32_t*)p;           p += 128;
  uint32_t* projb = (uint32_t*)p;         p += (size_t)SBTOT * 32 * 4;
  float* Syd = (float*)p;                 p += (size_t)SBTOT * 32 * 4;
  float* logpx = (float*)p;               p += (size_t)NT * SBTOT * 4;
  double* loss_acc = (double*)p;          p += 64;
  uint32_t* done_ctr = (uint32_t*)p;      p += 64;
  ushort* Vkpad2 = (ushort*)p;            p += (size_t)NX * 32 * 2;
  ushort* Vbf = (ushort*)p;               p += (size_t)NX * NZ * 2;
  ushort* samp16 = (ushort*)p;            p += (size_t)SBTOT * NZ * 2;
  float* W = (float*)p;                   p += (size_t)NB * 32 * 4;
  ushort* Uhi = (ushort*)p;               p += (size_t)NZ * NX * 2;
  ushort* Ulo = (ushort*)p;               p += (size_t)NZ * NX * 2;
  ushort* xinbf = (ushort*)p;             p += (size_t)NB * NX * 2;
  (void)ws_size; (void)in_sizes; (void)n_in; (void)out_size;

  // JAX: key(42) -> split 4 -> kz,kx,kA,kb
  uint32_t o0[4], o1[4];
  for (int j = 0; j < 4; ++j) tf2x32(0u, 42u, (uint32_t)j, (uint32_t)(4 + j), o0[j], o1[j]);
  uint32_t kz0 = o0[0], kz1 = o0[1];
  uint32_t kx0 = o0[2], kx1 = o0[3];
  uint32_t kA0 = o1[0], kA1 = o1[1];
  uint32_t kb0 = o1[2], kb1 = o1[3];

  kP0_prep<<<NX * NZ / 256, 256, 0, stream>>>(V, U, xin, z_bias, Vbf, Vkpad2,
                                              Uhi, Ulo, xinbf, baseq, d_lpz, basepz,
                                              loss_acc, done_ctr);
  k1w_mfma<<<1024 + NT, 256, 0, stream>>>(xinbf, Uhi, Ulo, z_bias, xin, Vkpad2,
                                          out + OFF_Q, d_lq, baseq, W,
                                          Ct, bpm, kA0, kA1, kb0, kb1);
  k2_samples<<<SBTOT, 256, 0, stream>>>(out + OFF_Q, d_lq, d_lpz, Ct, bpm, W,
                                        out + OFF_SAMP, samp16, Spack, qtail, ptail,
                                        projb, Syd, kz0, kz1);
  dim3 g3(NX / 128, SBTOT / 64);
  k3m_gemm<<<g3, 256, 0, stream>>>(samp16, Vbf, x_bias, base2,
                                   out + OFF_PS, out + OFF_XO, kx0, kx1);
  k6_mfma<<<SBTOT, 256, 0, stream>>>(base2, Vkpad2, xin, projb, Spack, Syd, logpx);
  dim3 g7(NT, 8);
  k7_reduce<<<g7, 64, 0, stream>>>(logpx, projb, qtail, ptail, baseq, d_lq,
                                   d_lpz, basepz, loss_acc, done_ctr, out + OFF_LOSS);
}